// Round 3
// baseline (261.464 us; speedup 1.0000x reference)
//
#include <hip/hip_runtime.h>

#define NB 8
#define CHW 6300
#define TT 500
#define OUT 128
#define NO 1024          // N*OUT chains
#define KPAD 6400        // K padded to 32*200
#define NK32 200         // K32 steps total
#define KSPLIT 2
#define KH (NK32 / KSPLIT)   // 100 k32-steps per split
#define TPAD 512

typedef __attribute__((ext_vector_type(8))) _Float16 f16x8;
typedef __attribute__((ext_vector_type(4))) float f32x4;

// ---------------- Kernel 1: pack W into MFMA B-fragment order ----------------
// Wp[hl][k32][osub][lane][8] f16; element: o=osub*16+(lane&15), c=k32*32+(lane>>4)*8+i
// hl=0: f16(W); hl=1: f16((W - f16(W)) * 2048)
__global__ __launch_bounds__(512) void packW(const float* __restrict__ W,
                                             _Float16* __restrict__ Wp) {
    const int tid = threadIdx.x;
    const int osub = tid >> 6;
    const int lane = tid & 63;
    const int k32 = blockIdx.x;      // 0..199
    const int hl = blockIdx.y;       // 0..1
    const int o = osub * 16 + (lane & 15);
    const int cb = k32 * 32 + (lane >> 4) * 8;

    union { _Float16 h[8]; uint4 u; } tmp;
#pragma unroll
    for (int i = 0; i < 8; i++) {
        int c = cb + i;
        float w = (c < CHW) ? W[(size_t)o * CHW + c] : 0.f;
        _Float16 hi = (_Float16)w;
        tmp.h[i] = (hl == 0) ? hi : (_Float16)((w - (float)hi) * 2048.f);
    }
    size_t lr = (((size_t)hl * NK32 + k32) * 8 + osub) * 64 + lane;
    *(uint4*)(Wp + lr * 8) = tmp.u;
}

// ---------------- Kernel 2: transpose+convert x[n][c][t] f32 -> xT[n][t][c] f16 ----
__global__ __launch_bounds__(256) void xpose(const float* __restrict__ x,
                                             _Float16* __restrict__ xT) {
    __shared__ _Float16 tile[32][33];
    const int c0 = blockIdx.x * 32;     // 0..6368
    const int t0 = blockIdx.y * 32;     // 0..480
    const int n = blockIdx.z;
    const int tx = threadIdx.x;         // 0..31
    const int ty = threadIdx.y;         // 0..7

#pragma unroll
    for (int j = 0; j < 4; j++) {
        int cl = ty + j * 8;
        int c = c0 + cl;
        int t = t0 + tx;
        float v = (c < CHW && t < TT) ? x[((size_t)n * CHW + c) * TT + t] : 0.f;
        tile[cl][tx] = (_Float16)v;
    }
    __syncthreads();
#pragma unroll
    for (int j = 0; j < 4; j++) {
        int tl = ty + j * 8;
        xT[((size_t)n * TPAD + t0 + tl) * KPAD + c0 + tx] = tile[tx][tl];
    }
}

// ---------------- Kernel 3: MFMA GEMM vp[ks][t][n][o] = xT * Wp ----------------
// block: 256 thr = 4 waves, tile 32t x 128o, K-chunk = 100 k32 steps (3200 c)
// wave w owns o-range [w*32, w*32+32): 2 osub x 2 hl accumulators x 2 tsub
__global__ __launch_bounds__(256) void gemm(const _Float16* __restrict__ xT,
                                            const _Float16* __restrict__ Wp,
                                            float* __restrict__ vp) {
    const int tt = blockIdx.x;       // 0..15 -> t0 = tt*32
    const int n  = blockIdx.y;       // 0..7
    const int ks = blockIdx.z;       // 0..1
    const int tid = threadIdx.x;
    const int wave = tid >> 6;       // 0..3
    const int lane = tid & 63;
    const int t0 = tt * 32;

    __shared__ _Float16 xs[2][32][128];   // 8KB per buf

    f32x4 acc[2][2][2] = {};   // [tsub][osub][hl]

    const size_t xbase = ((size_t)n * TPAD + t0) * KPAD + (size_t)ks * (KH * 32);
    // staging map: idx = q*256+tid -> row=idx>>4 (t), ch=idx&15 (16B chunk of 8 f16)
    const int srow0 = tid >> 4;             // q=0 row
    const int sch = tid & 15;
    const int srow1 = (256 + tid) >> 4;     // q=1 row = srow0+16

    uint4 r0, r1;
    // prologue: load chunk 0
    r0 = *(const uint4*)(xT + xbase + (size_t)srow0 * KPAD + sch * 8);
    r1 = *(const uint4*)(xT + xbase + (size_t)srow1 * KPAD + sch * 8);
    *(uint4*)&xs[0][srow0][sch * 8] = r0;
    *(uint4*)&xs[0][srow1][sch * 8] = r1;
    __syncthreads();

    for (int it = 0; it < 25; ++it) {
        const int cur = it & 1;
        if (it < 24) {
            size_t off = xbase + (size_t)(it + 1) * 128;
            r0 = *(const uint4*)(xT + off + (size_t)srow0 * KPAD + sch * 8);
            r1 = *(const uint4*)(xT + off + (size_t)srow1 * KPAD + sch * 8);
        }
        // compute 4 k32 steps from buf cur
        const int k32b = ks * KH + it * 4;
#pragma unroll
        for (int j = 0; j < 4; ++j) {
            f16x8 a0 = *(const f16x8*)&xs[cur][(lane & 15)][j * 32 + (lane >> 4) * 8];
            f16x8 a1 = *(const f16x8*)&xs[cur][16 + (lane & 15)][j * 32 + (lane >> 4) * 8];
#pragma unroll
            for (int os = 0; os < 2; ++os) {
#pragma unroll
                for (int hl = 0; hl < 2; ++hl) {
                    const f16x8 b = *(const f16x8*)(Wp +
                        ((((size_t)hl * NK32 + k32b + j) * 8 + wave * 2 + os) * 64 + lane) * 8);
                    acc[0][os][hl] = __builtin_amdgcn_mfma_f32_16x16x32_f16(a0, b, acc[0][os][hl], 0, 0, 0);
                    acc[1][os][hl] = __builtin_amdgcn_mfma_f32_16x16x32_f16(a1, b, acc[1][os][hl], 0, 0, 0);
                }
            }
        }
        if (it < 24) {
            *(uint4*)&xs[cur ^ 1][srow0][sch * 8] = r0;
            *(uint4*)&xs[cur ^ 1][srow1][sch * 8] = r1;
        }
        __syncthreads();
    }

    // epilogue: v = hi + lo/2048; D layout: col=lane&15 (o), row=(lane>>4)*4+r (t)
    const float inv = 1.f / 2048.f;
#pragma unroll
    for (int ts = 0; ts < 2; ++ts) {
#pragma unroll
        for (int os = 0; os < 2; ++os) {
#pragma unroll
            for (int r = 0; r < 4; ++r) {
                int t = t0 + ts * 16 + (lane >> 4) * 4 + r;
                if (t < TT) {
                    int o = wave * 32 + os * 16 + (lane & 15);
                    vp[(((size_t)ks * TT + t) * NB + n) * OUT + o] =
                        acc[ts][os][0][r] + acc[ts][os][1][r] * inv;
                }
            }
        }
    }
}

// ---------------- Kernel 4: fused alpha-filter + spike scan (2 K-partials) ----
__global__ __launch_bounds__(64) void scanspike(const float* __restrict__ v,
                                                float* __restrict__ out) {
    const int lane = threadIdx.x;                // 0..63
    const int gid = blockIdx.x * 64 + lane;      // 0..1023

    const float RA = 0.9048374180359595f;        // exp(-TS/TAU_SR)
    const float CA = 0.27182818284590452f;       // (TS/TAU_SR)*e
    const float RS = 0.36787944117144233f;       // exp(-TS/TAU_REF)
    const float CS = -54.365636569180902f;       // -SCALE_REF*THETA*(TS/TAU_REF)*e
    const float THETA = 10.0f;

    const float* p0 = v;
    const float* p1 = v + (size_t)TT * NO;

    __shared__ float sbuf[64][65];

    float Aa = 0.f, Ba = 0.f, As = 0.f, Bs = 0.f;

    for (int tb = 0; tb < 8; tb++) {
        const int t0 = tb * 64;
        const int cnt = (tb == 7) ? (TT - 448) : 64;   // 64,...,64,52

        float vv[64];
        if (cnt == 64) {
#pragma unroll
            for (int i = 0; i < 64; i++)
                vv[i] = p0[(size_t)(t0 + i) * NO + gid] + p1[(size_t)(t0 + i) * NO + gid];
#pragma unroll
            for (int i = 0; i < 64; i++) {
                float ua = Aa;
                float Bpa = Ba + CA * vv[i];
                Aa = RA * (Aa + Bpa);
                Ba = RA * Bpa;
                float u = ua + As;
                float s = (u >= THETA) ? 1.f : 0.f;
                float Bps = Bs + CS * s;
                As = RS * (As + Bps);
                Bs = RS * Bps;
                sbuf[lane][i] = s;
            }
        } else {
#pragma unroll
            for (int i = 0; i < 52; i++)
                vv[i] = p0[(size_t)(t0 + i) * NO + gid] + p1[(size_t)(t0 + i) * NO + gid];
#pragma unroll
            for (int i = 0; i < 52; i++) {
                float ua = Aa;
                float Bpa = Ba + CA * vv[i];
                Aa = RA * (Aa + Bpa);
                Ba = RA * Bpa;
                float u = ua + As;
                float s = (u >= THETA) ? 1.f : 0.f;
                float Bps = Bs + CS * s;
                As = RS * (As + Bps);
                Bs = RS * Bps;
                sbuf[lane][i] = s;
            }
        }
        __syncthreads();
        for (int r = 0; r < 64; r++) {
            int gr = blockIdx.x * 64 + r;
            int nr = gr >> 7;
            int orr = gr & 127;
            if (lane < cnt)
                out[((size_t)nr * OUT + orr) * TT + t0 + lane] = sbuf[r][lane];
        }
        __syncthreads();
    }
}

extern "C" void kernel_launch(void* const* d_in, const int* in_sizes, int n_in,
                              void* d_out, int out_size, void* d_ws, size_t ws_size,
                              hipStream_t stream) {
    const float* x = (const float*)d_in[0];   // [8,2,50,63,500] fp32
    const float* W = (const float*)d_in[1];   // [128,6300] fp32
    float* out = (float*)d_out;               // [8,128,1,1,500] fp32

    // ws layout
    _Float16* xT = (_Float16*)d_ws;                                   // 8*512*6400*2   = 52,428,800
    _Float16* Wp = (_Float16*)((char*)d_ws + 52428800);               // 2*200*8*64*8*2 =  3,276,800
    float*    vp = (float*)((char*)d_ws + 52428800 + 3276800);        // 2*500*1024*4   =  4,096,000

    packW<<<dim3(NK32, 2), 512, 0, stream>>>(W, Wp);
    xpose<<<dim3(KPAD / 32, TPAD / 32, NB), dim3(32, 8), 0, stream>>>(x, xT);
    gemm<<<dim3(16, NB, KSPLIT), 256, 0, stream>>>(xT, Wp, vp);
    scanspike<<<16, 64, 0, stream>>>(vp, out);
}

// Round 4
// 126.310 us; speedup vs baseline: 2.0700x; 2.0700x over previous
//
#include <hip/hip_runtime.h>

#define NB 8
#define CHW 6300
#define TT 500
#define OUT 128
#define NO 1024          // N*OUT chains
#define KPAD 6400        // K padded to 32*200
#define NK32 200         // K32 steps total
#define KSPLIT 2
#define KH (NK32 / KSPLIT)   // 100 k32-steps per split
#define TPAD 512

typedef __attribute__((ext_vector_type(8))) _Float16 f16x8;
typedef __attribute__((ext_vector_type(4))) float f32x4;

// ---------------- Kernel 1: pack W into MFMA B-fragment order ----------------
// Wp[hl][k32][osub][lane][8] f16; element: o=osub*16+(lane&15), c=k32*32+(lane>>4)*8+i
// hl=0: f16(W); hl=1: f16((W - f16(W)) * 2048)
__global__ __launch_bounds__(512) void packW(const float* __restrict__ W,
                                             _Float16* __restrict__ Wp) {
    const int tid = threadIdx.x;
    const int osub = tid >> 6;
    const int lane = tid & 63;
    const int k32 = blockIdx.x;      // 0..199
    const int hl = blockIdx.y;       // 0..1
    const int o = osub * 16 + (lane & 15);
    const int cb = k32 * 32 + (lane >> 4) * 8;

    union { _Float16 h[8]; uint4 u; } tmp;
#pragma unroll
    for (int i = 0; i < 8; i++) {
        int c = cb + i;
        float w = (c < CHW) ? W[(size_t)o * CHW + c] : 0.f;
        _Float16 hi = (_Float16)w;
        tmp.h[i] = (hl == 0) ? hi : (_Float16)((w - (float)hi) * 2048.f);
    }
    size_t lr = (((size_t)hl * NK32 + k32) * 8 + osub) * 64 + lane;
    *(uint4*)(Wp + lr * 8) = tmp.u;
}

// ---------------- Kernel 2: transpose+convert x[n][c][t] f32 -> xT[n][t][c] f16 ----
__global__ __launch_bounds__(256) void xpose(const float* __restrict__ x,
                                             _Float16* __restrict__ xT) {
    __shared__ _Float16 tile[32][33];
    const int c0 = blockIdx.x * 32;     // 0..6368
    const int t0 = blockIdx.y * 32;     // 0..480
    const int n = blockIdx.z;
    const int tx = threadIdx.x;         // 0..31
    const int ty = threadIdx.y;         // 0..7

#pragma unroll
    for (int j = 0; j < 4; j++) {
        int cl = ty + j * 8;
        int c = c0 + cl;
        int t = t0 + tx;
        float v = (c < CHW && t < TT) ? x[((size_t)n * CHW + c) * TT + t] : 0.f;
        tile[cl][tx] = (_Float16)v;
    }
    __syncthreads();
#pragma unroll
    for (int j = 0; j < 4; j++) {
        int tl = ty + j * 8;
        xT[((size_t)n * TPAD + t0 + tl) * KPAD + c0 + tx] = tile[tx][tl];
    }
}

// ---------------- Kernel 3: MFMA GEMM vp[ks][t][n][o] = xT * Wp ----------------
__global__ __launch_bounds__(256) void gemm(const _Float16* __restrict__ xT,
                                            const _Float16* __restrict__ Wp,
                                            float* __restrict__ vp) {
    const int tt = blockIdx.x;       // 0..15 -> t0 = tt*32
    const int n  = blockIdx.y;       // 0..7
    const int ks = blockIdx.z;       // 0..1
    const int tid = threadIdx.x;
    const int wave = tid >> 6;       // 0..3
    const int lane = tid & 63;
    const int t0 = tt * 32;

    __shared__ _Float16 xs[2][32][128];   // 8KB per buf

    f32x4 acc[2][2][2] = {};   // [tsub][osub][hl]

    const size_t xbase = ((size_t)n * TPAD + t0) * KPAD + (size_t)ks * (KH * 32);
    const int srow0 = tid >> 4;             // q=0 row
    const int sch = tid & 15;
    const int srow1 = (256 + tid) >> 4;     // q=1 row = srow0+16

    uint4 r0, r1;
    r0 = *(const uint4*)(xT + xbase + (size_t)srow0 * KPAD + sch * 8);
    r1 = *(const uint4*)(xT + xbase + (size_t)srow1 * KPAD + sch * 8);
    *(uint4*)&xs[0][srow0][sch * 8] = r0;
    *(uint4*)&xs[0][srow1][sch * 8] = r1;
    __syncthreads();

    for (int it = 0; it < 25; ++it) {
        const int cur = it & 1;
        if (it < 24) {
            size_t off = xbase + (size_t)(it + 1) * 128;
            r0 = *(const uint4*)(xT + off + (size_t)srow0 * KPAD + sch * 8);
            r1 = *(const uint4*)(xT + off + (size_t)srow1 * KPAD + sch * 8);
        }
        const int k32b = ks * KH + it * 4;
#pragma unroll
        for (int j = 0; j < 4; ++j) {
            f16x8 a0 = *(const f16x8*)&xs[cur][(lane & 15)][j * 32 + (lane >> 4) * 8];
            f16x8 a1 = *(const f16x8*)&xs[cur][16 + (lane & 15)][j * 32 + (lane >> 4) * 8];
#pragma unroll
            for (int os = 0; os < 2; ++os) {
#pragma unroll
                for (int hl = 0; hl < 2; ++hl) {
                    const f16x8 b = *(const f16x8*)(Wp +
                        ((((size_t)hl * NK32 + k32b + j) * 8 + wave * 2 + os) * 64 + lane) * 8);
                    acc[0][os][hl] = __builtin_amdgcn_mfma_f32_16x16x32_f16(a0, b, acc[0][os][hl], 0, 0, 0);
                    acc[1][os][hl] = __builtin_amdgcn_mfma_f32_16x16x32_f16(a1, b, acc[1][os][hl], 0, 0, 0);
                }
            }
        }
        if (it < 24) {
            *(uint4*)&xs[cur ^ 1][srow0][sch * 8] = r0;
            *(uint4*)&xs[cur ^ 1][srow1][sch * 8] = r1;
        }
        __syncthreads();
    }

    const float inv = 1.f / 2048.f;
#pragma unroll
    for (int ts = 0; ts < 2; ++ts) {
#pragma unroll
        for (int os = 0; os < 2; ++os) {
#pragma unroll
            for (int r = 0; r < 4; ++r) {
                int t = t0 + ts * 16 + (lane >> 4) * 4 + r;
                if (t < TT) {
                    int o = wave * 32 + os * 16 + (lane & 15);
                    vp[(((size_t)ks * TT + t) * NB + n) * OUT + o] =
                        acc[ts][os][0][r] + acc[ts][os][1][r] * inv;
                }
            }
        }
    }
}

// ---------------- Kernel 4: wave-specialized alpha+spike scan ----------------
// 16 blocks x 256 thr (4 waves). Wave 0 runs the serial recursion from LDS;
// waves 1-3 prefetch the next 64-t slab (fusing the 2 K-partial sum) into a
// double-buffered chain-major LDS slab (pad 65 -> 65==1 mod 32 -> 2-way free).
#define SCN_RA 0.9048374180359595f        // exp(-TS/TAU_SR)
#define SCN_CA 0.27182818284590452f       // (TS/TAU_SR)*e
#define SCN_RS 0.36787944117144233f       // exp(-TS/TAU_REF)
#define SCN_CS -54.365636569180902f       // -SCALE_REF*THETA*(TS/TAU_REF)*e
#define SCN_TH 10.0f

__global__ __launch_bounds__(256) void scanspike(const float* __restrict__ v,
                                                 float* __restrict__ out) {
    const int tid = threadIdx.x;
    const int wave = tid >> 6;               // 0..3
    const int lane = tid & 63;
    const int g0 = blockIdx.x * 64;          // chain base

    const float* p0 = v;
    const float* p1 = v + (size_t)TT * NO;

    __shared__ float vbuf[2][64][65];        // [buf][chain][tloc]
    __shared__ float sbuf[64][65];           // [chain][tloc]

    // prologue: all 4 waves stage tb=0 (64 rows)
    for (int r = wave; r < 64; r += 4) {
        float a = p0[(size_t)r * NO + g0 + lane] + p1[(size_t)r * NO + g0 + lane];
        vbuf[0][lane][r] = a;
    }
    __syncthreads();

    float Aa = 0.f, Ba = 0.f, As = 0.f, Bs = 0.f;

    for (int tb = 0; tb < 8; ++tb) {
        const int cur = tb & 1;
        const int cnt = (tb == 7) ? 52 : 64;

        if (wave == 0) {
            // serial recursion over this slab, reading LDS (2-way banks, free)
            if (cnt == 64) {
#pragma unroll
                for (int i = 0; i < 64; ++i) {
                    float vt = vbuf[cur][lane][i];
                    float ua = Aa;
                    float Bpa = Ba + SCN_CA * vt;
                    Aa = SCN_RA * (Aa + Bpa);
                    Ba = SCN_RA * Bpa;
                    float u = ua + As;
                    float s = (u >= SCN_TH) ? 1.f : 0.f;
                    float Bps = Bs + SCN_CS * s;
                    As = SCN_RS * (As + Bps);
                    Bs = SCN_RS * Bps;
                    sbuf[lane][i] = s;
                }
            } else {
#pragma unroll
                for (int i = 0; i < 52; ++i) {
                    float vt = vbuf[cur][lane][i];
                    float ua = Aa;
                    float Bpa = Ba + SCN_CA * vt;
                    Aa = SCN_RA * (Aa + Bpa);
                    Ba = SCN_RA * Bpa;
                    float u = ua + As;
                    float s = (u >= SCN_TH) ? 1.f : 0.f;
                    float Bps = Bs + SCN_CS * s;
                    As = SCN_RS * (As + Bps);
                    Bs = SCN_RS * Bps;
                    sbuf[lane][i] = s;
                }
            }
        } else if (tb < 7) {
            // waves 1-3: prefetch slab tb+1 (fused K-partial reduction)
            const int nt0 = (tb + 1) * 64;
            const int ncnt = (tb == 6) ? 52 : 64;
            for (int r = wave - 1; r < ncnt; r += 3) {
                float a = p0[(size_t)(nt0 + r) * NO + g0 + lane] +
                          p1[(size_t)(nt0 + r) * NO + g0 + lane];
                vbuf[cur ^ 1][lane][r] = a;
            }
        }
        __syncthreads();

        // flush spikes: wave w handles rows w*16..w*16+15, lanes cover t (coalesced)
#pragma unroll
        for (int rr = 0; rr < 16; ++rr) {
            int r = wave * 16 + rr;
            int gr = g0 + r;
            int nr = gr >> 7;
            int orr = gr & 127;
            if (lane < cnt)
                out[((size_t)nr * OUT + orr) * TT + tb * 64 + lane] = sbuf[r][lane];
        }
        __syncthreads();
    }
}

extern "C" void kernel_launch(void* const* d_in, const int* in_sizes, int n_in,
                              void* d_out, int out_size, void* d_ws, size_t ws_size,
                              hipStream_t stream) {
    const float* x = (const float*)d_in[0];   // [8,2,50,63,500] fp32
    const float* W = (const float*)d_in[1];   // [128,6300] fp32
    float* out = (float*)d_out;               // [8,128,1,1,500] fp32

    _Float16* xT = (_Float16*)d_ws;                                   // 52,428,800 B
    _Float16* Wp = (_Float16*)((char*)d_ws + 52428800);               //  3,276,800 B
    float*    vp = (float*)((char*)d_ws + 52428800 + 3276800);        //  4,096,000 B

    packW<<<dim3(NK32, 2), 512, 0, stream>>>(W, Wp);
    xpose<<<dim3(KPAD / 32, TPAD / 32, NB), dim3(32, 8), 0, stream>>>(x, xT);
    gemm<<<dim3(16, NB, KSPLIT), 256, 0, stream>>>(xT, Wp, vp);
    scanspike<<<16, 256, 0, stream>>>(vp, out);
}

// Round 5
// 98.513 us; speedup vs baseline: 2.6541x; 1.2822x over previous
//
#include <hip/hip_runtime.h>

#define NB 8
#define CHW 6300
#define TT 500
#define OUT 128
#define NO 1024
#define KPAD 6400
#define NK32 200          // total k32 steps
#define KSPLIT 8
#define NKC (NK32/KSPLIT) // 25 k32 per block
#define TPAD 512

typedef __attribute__((ext_vector_type(8))) _Float16 f16x8;
typedef __attribute__((ext_vector_type(4))) float f32x4;

typedef const void __attribute__((address_space(1)))* gas1_t;
typedef void __attribute__((address_space(3)))* las3_t;

__device__ __forceinline__ void gload_lds16(const void* g, void* l) {
    __builtin_amdgcn_global_load_lds((gas1_t)g, (las3_t)l, 16, 0, 0);
}

// ---------------- Kernel 1: pack W into MFMA B-fragment order ----------------
// Wp[hl][k32][osub][lane][8]; o=osub*16+(lane&15), c=k32*32+(lane>>4)*8+i
__global__ __launch_bounds__(512) void packW(const float* __restrict__ W,
                                             _Float16* __restrict__ Wp) {
    const int tid = threadIdx.x;
    const int osub = tid >> 6;
    const int lane = tid & 63;
    const int k32 = blockIdx.x;
    const int hl = blockIdx.y;
    const int o = osub * 16 + (lane & 15);
    const int cb = k32 * 32 + (lane >> 4) * 8;

    union { _Float16 h[8]; uint4 u; } tmp;
#pragma unroll
    for (int i = 0; i < 8; i++) {
        int c = cb + i;
        float w = (c < CHW) ? W[(size_t)o * CHW + c] : 0.f;
        _Float16 hi = (_Float16)w;
        tmp.h[i] = (hl == 0) ? hi : (_Float16)((w - (float)hi) * 2048.f);
    }
    size_t lr = (((size_t)hl * NK32 + k32) * 8 + osub) * 64 + lane;
    *(uint4*)(Wp + lr * 8) = tmp.u;
}

// ---------------- Kernel 2: transpose+convert x[n][c][t] f32 -> xT[n][t][c] f16 ----
__global__ __launch_bounds__(256) void xpose(const float* __restrict__ x,
                                             _Float16* __restrict__ xT) {
    __shared__ _Float16 tile[32][33];
    const int c0 = blockIdx.x * 32;
    const int t0 = blockIdx.y * 32;
    const int n = blockIdx.z;
    const int tx = threadIdx.x;
    const int ty = threadIdx.y;

#pragma unroll
    for (int j = 0; j < 4; j++) {
        int cl = ty + j * 8;
        int c = c0 + cl;
        int t = t0 + tx;
        float v = (c < CHW && t < TT) ? x[((size_t)n * CHW + c) * TT + t] : 0.f;
        tile[cl][tx] = (_Float16)v;
    }
    __syncthreads();
#pragma unroll
    for (int j = 0; j < 4; j++) {
        int tl = ty + j * 8;
        xT[((size_t)n * TPAD + t0 + tl) * KPAD + c0 + tx] = tile[tx][tl];
    }
}

// ---------------- Kernel 3: MFMA GEMM, 128rows x 128o tiles, KSPLIT=8 ----------------
// rows r = n*512+t (contiguous in xT). 4 waves 2x2: wave tile 64r x 64o.
// A staged to LDS in frag order via global_load_lds; B reg-double-buffered from L2.
__global__ __launch_bounds__(256, 1) void gemm(const _Float16* __restrict__ xT,
                                               const _Float16* __restrict__ Wp,
                                               float* __restrict__ vp) {
    const int rt = blockIdx.x;       // 0..31 row tile
    const int ks = blockIdx.y;       // 0..7
    const int tid = threadIdx.x;
    const int wave = tid >> 6;
    const int lane = tid & 63;
    const int wr = wave >> 1;        // 0..1 row half
    const int wc = wave & 1;         // 0..1 o half
    const int r0 = rt * 128;
    const int k32_0 = ks * NKC;

    __shared__ _Float16 As[2][8][64 * 8];   // [buf][frag][lane*8] = 16KB

    f32x4 acc[4][4][2] = {};                // [ts][os][hl]
    f16x8 B0[4][2], B1[4][2];

    // staging duties: wave stages frags f = p*4 + wave, p=0..1
    const int f0 = wave;             // pass 0 frag
    const int f1 = 4 + wave;         // pass 1 frag
    const int arow0 = r0 + f0 * 16 + (lane & 15);
    const int arow1 = r0 + f1 * 16 + (lane & 15);
    const int acoff = (lane >> 4) * 8;

#define STAGE_A(it, buf)                                                              \
    {                                                                                 \
        int kc = (k32_0 + (it)) * 32 + acoff;                                         \
        gload_lds16(xT + (size_t)arow0 * KPAD + kc, &As[buf][f0][0]);                 \
        gload_lds16(xT + (size_t)arow1 * KPAD + kc, &As[buf][f1][0]);                 \
    }

#define LOAD_B(Bd, it)                                                                \
    {                                                                                 \
        _Pragma("unroll") for (int os = 0; os < 4; os++)                              \
            _Pragma("unroll") for (int hl = 0; hl < 2; hl++)                          \
                Bd[os][hl] = *(const f16x8*)(Wp +                                     \
                    ((((size_t)hl * NK32 + k32_0 + (it)) * 8 + wc * 4 + os) * 64 +    \
                     lane) * 8);                                                      \
    }

#define MFMA_STEP(it, Bc)                                                             \
    {                                                                                 \
        f16x8 a[4];                                                                   \
        _Pragma("unroll") for (int ts = 0; ts < 4; ts++)                              \
            a[ts] = *(const f16x8*)&As[(it) & 1][wr * 4 + ts][lane * 8];              \
        _Pragma("unroll") for (int ts = 0; ts < 4; ts++)                              \
            _Pragma("unroll") for (int os = 0; os < 4; os++)                          \
                _Pragma("unroll") for (int hl = 0; hl < 2; hl++)                      \
                    acc[ts][os][hl] = __builtin_amdgcn_mfma_f32_16x16x32_f16(         \
                        a[ts], Bc[os][hl], acc[ts][os][hl], 0, 0, 0);                 \
    }

    // prologue
    STAGE_A(0, 0);
    LOAD_B(B0, 0);
    __syncthreads();

    for (int ith = 0; ith < 12; ++ith) {
        const int it0 = 2 * ith;
        // even step: compute it0 with B0, prefetch it0+1
        STAGE_A(it0 + 1, 1);
        LOAD_B(B1, it0 + 1);
        MFMA_STEP(it0, B0);
        __syncthreads();
        // odd step: compute it0+1 with B1, prefetch it0+2
        STAGE_A(it0 + 2, 0);
        LOAD_B(B0, it0 + 2);
        MFMA_STEP(it0 + 1, B1);
        __syncthreads();
    }
    // final it = 24 (buf 0), no prefetch
    MFMA_STEP(24, B0);

    // epilogue: combine hl, store vp[ks][t][n][o]
    const float inv = 1.f / 2048.f;
#pragma unroll
    for (int ts = 0; ts < 4; ts++)
#pragma unroll
        for (int os = 0; os < 4; os++)
#pragma unroll
            for (int rg = 0; rg < 4; rg++) {
                int rl = wr * 64 + ts * 16 + (lane >> 4) * 4 + rg;
                int rgl = r0 + rl;
                int n = rgl >> 9;
                int t = rgl & 511;
                if (t < TT) {
                    int o = wc * 64 + os * 16 + (lane & 15);
                    vp[(((size_t)ks * TT + t) * NB + n) * OUT + o] =
                        acc[ts][os][0][rg] + acc[ts][os][1][rg] * inv;
                }
            }
#undef STAGE_A
#undef LOAD_B
#undef MFMA_STEP
}

// ---------------- Kernel 4: wave-specialized alpha+spike scan ----------------
// 16 blocks x 512 thr. Wave 0: batched-register serial recursion (short critical
// path via G/H reformulation); waves 1-7: stage 8-partial sums into vbuf[t][chain].
#define SCN_RA 0.9048374180359595f       // exp(-0.1)
#define SCN_RACA 0.24596031111569496f    // RA*CA = 0.1*e^0.9
#define SCN_RS 0.36787944117144233f      // exp(-1)
#define SCN_RSCS -20.0f                  // RS*CS (CS = -20e)
#define SCN_RSCS2 -40.0f                 // 2*RS*CS
#define SCN_RSRSCS -7.3575888234288467f  // RS*RS*CS
#define SCN_TH 10.0f

#define CHAIN_STEP(i)                                                   \
    {                                                                   \
        float ua = Aa;                                                  \
        float w = fmaf(SCN_RS, G, ua);                                  \
        float u = sp ? (w + SCN_RSCS) : w;                              \
        bool sn = (u >= SCN_TH);                                        \
        sbuf[i][lane] = sn ? 1.f : 0.f;                                 \
        float Gb = fmaf(SCN_RS, G, H);                                  \
        G = sp ? (Gb + SCN_RSCS2) : Gb;                                 \
        float Hb = SCN_RS * H;                                          \
        H = sp ? (Hb + SCN_RSRSCS) : Hb;                                \
        sp = sn;                                                        \
        Ba = fmaf(SCN_RA, Ba, SCN_RACA * vv[i]);                        \
        Aa = fmaf(SCN_RA, Aa, Ba);                                      \
    }

__global__ __launch_bounds__(512) void scanspike(const float* __restrict__ vp,
                                                 float* __restrict__ out) {
    const int tid = threadIdx.x;
    const int wave = tid >> 6;
    const int lane = tid & 63;
    const int g0 = blockIdx.x * 64;
    const int gidx = g0 + lane;
    const int cn = gidx >> 7;        // n of this lane's chain
    const int co = gidx & 127;       // o of this lane's chain

    __shared__ float vbuf[2][64][64];   // [buf][tloc][chain] - all row-contig access
    __shared__ float sbuf[64][65];      // [tloc][chain+pad]

    // prologue: all 8 waves stage slab 0
    for (int r = wave; r < 64; r += 8) {
        float a = 0.f;
#pragma unroll
        for (int k = 0; k < 8; k++)
            a += vp[(((size_t)k * TT + r) * NB + cn) * OUT + co];
        vbuf[0][r][lane] = a;
    }
    __syncthreads();

    float Aa = 0.f, Ba = 0.f, G = 0.f, H = 0.f;
    bool sp = false;

    for (int tb = 0; tb < 8; ++tb) {
        const int cur = tb & 1;
        const int t0 = tb * 64;
        const int cnt = (tb == 7) ? 52 : 64;

        if (wave == 0) {
            if (cnt == 64) {
                float vv[64];
#pragma unroll
                for (int i = 0; i < 64; ++i) vv[i] = vbuf[cur][i][lane];
#pragma unroll
                for (int i = 0; i < 64; ++i) CHAIN_STEP(i)
            } else {
                float vv[52];
#pragma unroll
                for (int i = 0; i < 52; ++i) vv[i] = vbuf[cur][i][lane];
#pragma unroll
                for (int i = 0; i < 52; ++i) CHAIN_STEP(i)
            }
        } else if (tb < 7) {
            const int nt0 = t0 + 64;
            const int ncnt = (tb == 6) ? 52 : 64;
            for (int r = wave - 1; r < ncnt; r += 7) {
                float a = 0.f;
#pragma unroll
                for (int k = 0; k < 8; k++)
                    a += vp[(((size_t)k * TT + nt0 + r) * NB + cn) * OUT + co];
                vbuf[cur ^ 1][r][lane] = a;
            }
        }
        __syncthreads();

        // flush: wave handles 8 chain rows; lanes cover t (coalesced)
#pragma unroll
        for (int j = 0; j < 8; ++j) {
            int r = wave * 8 + j;
            int gr = g0 + r;
            int n = gr >> 7;
            int o = gr & 127;
            if (lane < cnt)
                out[((size_t)n * OUT + o) * TT + t0 + lane] = sbuf[lane][r];
        }
        __syncthreads();
    }
}

extern "C" void kernel_launch(void* const* d_in, const int* in_sizes, int n_in,
                              void* d_out, int out_size, void* d_ws, size_t ws_size,
                              hipStream_t stream) {
    const float* x = (const float*)d_in[0];   // [8,2,50,63,500] fp32
    const float* W = (const float*)d_in[1];   // [128,6300] fp32
    float* out = (float*)d_out;               // [8,128,1,1,500] fp32

    _Float16* xT = (_Float16*)d_ws;                                   // 52,428,800 B
    _Float16* Wp = (_Float16*)((char*)d_ws + 52428800);               //  3,276,800 B
    float*    vp = (float*)((char*)d_ws + 52428800 + 3276800);        // 16,384,000 B

    packW<<<dim3(NK32, 2), 512, 0, stream>>>(W, Wp);
    xpose<<<dim3(KPAD / 32, TPAD / 32, NB), dim3(32, 8), 0, stream>>>(x, xT);
    gemm<<<dim3(32, KSPLIT), 256, 0, stream>>>(xT, Wp, vp);
    scanspike<<<16, 512, 0, stream>>>(vp, out);
}

// Round 6
// 67.568 us; speedup vs baseline: 3.8696x; 1.4580x over previous
//
#include <hip/hip_runtime.h>

#define NB 8
#define CHW 6300
#define TT 500
#define OUT 128
#define NO 1024
#define NK32 200          // total k32 steps (padded: 6300 -> 6400)
#define KSPLIT 8
#define NKC (NK32/KSPLIT) // 25 k32 per block

typedef __attribute__((ext_vector_type(8))) _Float16 f16x8;
typedef __attribute__((ext_vector_type(4))) float f32x4;

// ---------------- Kernel 1: pack W into MFMA A-fragment order ----------------
// Wp[hl][k32][osub][lane][8]; o=osub*16+(lane&15), c=k32*32+(lane>>4)*8+i
// hl=0: f16(W); hl=1: f16((W - f16(W)) * 2048). Zero-padded for c>=CHW.
__global__ __launch_bounds__(512) void packW(const float* __restrict__ W,
                                             _Float16* __restrict__ Wp) {
    const int tid = threadIdx.x;
    const int osub = tid >> 6;
    const int lane = tid & 63;
    const int k32 = blockIdx.x;
    const int hl = blockIdx.y;
    const int o = osub * 16 + (lane & 15);
    const int cb = k32 * 32 + (lane >> 4) * 8;

    union { _Float16 h[8]; uint4 u; } tmp;
#pragma unroll
    for (int i = 0; i < 8; i++) {
        int c = cb + i;
        float w = (c < CHW) ? W[(size_t)o * CHW + c] : 0.f;
        _Float16 hi = (_Float16)w;
        tmp.h[i] = (hl == 0) ? hi : (_Float16)((w - (float)hi) * 2048.f);
    }
    size_t lr = (((size_t)hl * NK32 + k32) * 8 + osub) * 64 + lane;
    *(uint4*)(Wp + lr * 8) = tmp.u;
}

// ---------------- Kernel 2: fused transpose+convert+MFMA GEMM ----------------
// v[t][n][o] = sum_c W[o][c] * x[n][c][t].  A = W (o x c, from Wp, L2-resident),
// B = x (c x t) read DIRECTLY from [n][c][t] fp32 layout, cvt f16 in-reg,
// staged via 8KB dbuf LDS. Block: 4 waves; tile 64t x 128o; KSPLIT=8.
// Wave w stages t-frag w and computes o-frags {2w, 2w+1} over all 4 t-frags.
__global__ __launch_bounds__(256, 2) void gemm(const float* __restrict__ x,
                                               const _Float16* __restrict__ Wp,
                                               float* __restrict__ vp) {
    // bijective XCD-chunk swizzle: logical neighbors (same chunk of 64) share an XCD
    const int L = blockIdx.x;                 // 0..511
    const int logical = (L & 7) * 64 + (L >> 3);
    const int tb = logical & 7;               // t-block (64 t)
    const int n  = (logical >> 3) & 7;        // batch
    const int ks = logical >> 6;              // k-split 0..7

    const int tid = threadIdx.x;
    const int wave = tid >> 6;
    const int lane = tid & 63;
    const int l15 = lane & 15;
    const int lg  = lane >> 4;                // 0..3
    const int k32_0 = ks * NKC;

    __shared__ _Float16 Bs[2][4][512];        // [buf][tfrag][lane*8] = 8KB

    // staging coords: wave stages t-frag == wave
    const int t_st = tb * 64 + wave * 16 + l15;
    const bool t_ok = (t_st < TT);
    const float* xrow = x + (size_t)n * CHW * TT + t_st;   // + c*TT per element

    f32x4 acc[2][4][2] = {};                  // [ofrag][tfrag][hl]
    f16x8 Ar0[2][2], Ar1[2][2];               // A dbuf [ofrag][hl]
    float xvA[8], xvB[8];                     // x prefetch dbuf (static idx)

#define XLOAD(xv, it)                                                              \
    {                                                                              \
        const int cb_ = (k32_0 + (it)) * 32 + lg * 8;                              \
        if (((k32_0 + (it) + 1) * 32 <= CHW) && t_ok) {                            \
            _Pragma("unroll") for (int i = 0; i < 8; i++)                          \
                xv[i] = xrow[(size_t)(cb_ + i) * TT];                              \
        } else {                                                                   \
            _Pragma("unroll") for (int i = 0; i < 8; i++)                          \
                xv[i] = (t_ok && (cb_ + i) < CHW) ? xrow[(size_t)(cb_ + i) * TT]   \
                                                  : 0.f;                           \
        }                                                                          \
    }

#define XWRITE(xv, buf)                                                            \
    {                                                                              \
        union { _Float16 h[8]; uint4 u; } tw_;                                     \
        _Pragma("unroll") for (int i = 0; i < 8; i++) tw_.h[i] = (_Float16)xv[i];  \
        *(uint4*)&Bs[buf][wave][lane * 8] = tw_.u;                                 \
    }

#define ALOAD(Ar, it)                                                              \
    _Pragma("unroll") for (int of = 0; of < 2; of++)                               \
        _Pragma("unroll") for (int hl = 0; hl < 2; hl++)                           \
            Ar[of][hl] = *(const f16x8*)(Wp +                                      \
                ((((size_t)hl * NK32 + k32_0 + (it)) * 8 + wave * 2 + of) * 64 +   \
                 lane) * 8);

#define COMPUTE(buf, Ar)                                                           \
    {                                                                              \
        f16x8 bfr[4];                                                              \
        _Pragma("unroll") for (int tf = 0; tf < 4; tf++)                           \
            bfr[tf] = *(const f16x8*)&Bs[buf][tf][lane * 8];                       \
        _Pragma("unroll") for (int of = 0; of < 2; of++)                           \
            _Pragma("unroll") for (int tf = 0; tf < 4; tf++)                       \
                _Pragma("unroll") for (int hl = 0; hl < 2; hl++)                   \
                    acc[of][tf][hl] = __builtin_amdgcn_mfma_f32_16x16x32_f16(      \
                        Ar[of][hl], bfr[tf], acc[of][tf][hl], 0, 0, 0);            \
    }

    // prologue: it0 and it1 in flight
    XLOAD(xvA, 0)
    XLOAD(xvB, 1)
    ALOAD(Ar0, 0)
    XWRITE(xvA, 0)
    ALOAD(Ar1, 1)
    __syncthreads();

    // 12 pairs handle it=0..23; epilogue handles it=24
    for (int p = 0; p < 12; ++p) {
        const int it = 2 * p;
        // even step
        XLOAD(xvA, it + 2)
        COMPUTE(0, Ar0)
        XWRITE(xvB, 1)
        ALOAD(Ar0, it + 2)
        __syncthreads();
        // odd step
        if (p < 11) { XLOAD(xvB, it + 3) }
        COMPUTE(1, Ar1)
        XWRITE(xvA, 0)
        if (p < 11) { ALOAD(Ar1, it + 3) }
        __syncthreads();
    }
    COMPUTE(0, Ar0)

    // epilogue: D layout col(l&15)=t, row=(l>>4)*4+r = o-within-frag
    const float inv = 1.f / 2048.f;
#pragma unroll
    for (int of = 0; of < 2; of++) {
        const int o0 = (wave * 2 + of) * 16 + lg * 4;
#pragma unroll
        for (int tf = 0; tf < 4; tf++) {
            const int t = tb * 64 + tf * 16 + l15;
            if (t < TT) {
                f32x4 vo;
#pragma unroll
                for (int r = 0; r < 4; r++)
                    vo[r] = acc[of][tf][0][r] + acc[of][tf][1][r] * inv;
                *(f32x4*)(vp + (((size_t)ks * TT + t) * NB + n) * OUT + o0) = vo;
            }
        }
    }
#undef XLOAD
#undef XWRITE
#undef ALOAD
#undef COMPUTE
}

// ---------------- Kernel 3: wave-specialized alpha+spike scan ----------------
// 16 blocks x 512 thr. Wave 0: batched-register serial recursion (short critical
// path via G/H reformulation); waves 1-7: stage 8-partial sums into vbuf[t][chain].
#define SCN_RA 0.9048374180359595f       // exp(-0.1)
#define SCN_RACA 0.24596031111569496f    // RA*CA = 0.1*e^0.9
#define SCN_RS 0.36787944117144233f      // exp(-1)
#define SCN_RSCS -20.0f                  // RS*CS (CS = -20e)
#define SCN_RSCS2 -40.0f                 // 2*RS*CS
#define SCN_RSRSCS -7.3575888234288467f  // RS*RS*CS
#define SCN_TH 10.0f

#define CHAIN_STEP(i)                                                   \
    {                                                                   \
        float ua = Aa;                                                  \
        float w = fmaf(SCN_RS, G, ua);                                  \
        float u = sp ? (w + SCN_RSCS) : w;                              \
        bool sn = (u >= SCN_TH);                                        \
        sbuf[i][lane] = sn ? 1.f : 0.f;                                 \
        float Gb = fmaf(SCN_RS, G, H);                                  \
        G = sp ? (Gb + SCN_RSCS2) : Gb;                                 \
        float Hb = SCN_RS * H;                                          \
        H = sp ? (Hb + SCN_RSRSCS) : Hb;                                \
        sp = sn;                                                        \
        Ba = fmaf(SCN_RA, Ba, SCN_RACA * vv[i]);                        \
        Aa = fmaf(SCN_RA, Aa, Ba);                                      \
    }

__global__ __launch_bounds__(512) void scanspike(const float* __restrict__ vp,
                                                 float* __restrict__ out) {
    const int tid = threadIdx.x;
    const int wave = tid >> 6;
    const int lane = tid & 63;
    const int g0 = blockIdx.x * 64;
    const int gidx = g0 + lane;
    const int cn = gidx >> 7;        // n of this lane's chain
    const int co = gidx & 127;       // o of this lane's chain

    __shared__ float vbuf[2][64][64];   // [buf][tloc][chain]
    __shared__ float sbuf[64][65];      // [tloc][chain+pad]

    for (int r = wave; r < 64; r += 8) {
        float a = 0.f;
#pragma unroll
        for (int k = 0; k < 8; k++)
            a += vp[(((size_t)k * TT + r) * NB + cn) * OUT + co];
        vbuf[0][r][lane] = a;
    }
    __syncthreads();

    float Aa = 0.f, Ba = 0.f, G = 0.f, H = 0.f;
    bool sp = false;

    for (int tb = 0; tb < 8; ++tb) {
        const int cur = tb & 1;
        const int t0 = tb * 64;
        const int cnt = (tb == 7) ? 52 : 64;

        if (wave == 0) {
            if (cnt == 64) {
                float vv[64];
#pragma unroll
                for (int i = 0; i < 64; ++i) vv[i] = vbuf[cur][i][lane];
#pragma unroll
                for (int i = 0; i < 64; ++i) CHAIN_STEP(i)
            } else {
                float vv[52];
#pragma unroll
                for (int i = 0; i < 52; ++i) vv[i] = vbuf[cur][i][lane];
#pragma unroll
                for (int i = 0; i < 52; ++i) CHAIN_STEP(i)
            }
        } else if (tb < 7) {
            const int nt0 = t0 + 64;
            const int ncnt = (tb == 6) ? 52 : 64;
            for (int r = wave - 1; r < ncnt; r += 7) {
                float a = 0.f;
#pragma unroll
                for (int k = 0; k < 8; k++)
                    a += vp[(((size_t)k * TT + nt0 + r) * NB + cn) * OUT + co];
                vbuf[cur ^ 1][r][lane] = a;
            }
        }
        __syncthreads();

#pragma unroll
        for (int j = 0; j < 8; ++j) {
            int r = wave * 8 + j;
            int gr = g0 + r;
            int nn = gr >> 7;
            int oo = gr & 127;
            if (lane < cnt)
                out[((size_t)nn * OUT + oo) * TT + t0 + lane] = sbuf[lane][r];
        }
        __syncthreads();
    }
}

extern "C" void kernel_launch(void* const* d_in, const int* in_sizes, int n_in,
                              void* d_out, int out_size, void* d_ws, size_t ws_size,
                              hipStream_t stream) {
    const float* x = (const float*)d_in[0];   // [8,2,50,63,500] fp32
    const float* W = (const float*)d_in[1];   // [128,6300] fp32
    float* out = (float*)d_out;               // [8,128,1,1,500] fp32

    _Float16* Wp = (_Float16*)d_ws;                         // 3,276,800 B
    float*    vp = (float*)((char*)d_ws + 3276800);         // 16,384,000 B

    packW<<<dim3(NK32, 2), 512, 0, stream>>>(W, Wp);
    gemm<<<512, 256, 0, stream>>>(x, Wp, vp);
    scanspike<<<16, 512, 0, stream>>>(vp, out);
}

// Round 7
// 60.598 us; speedup vs baseline: 4.3148x; 1.1150x over previous
//
#include <hip/hip_runtime.h>

#define NB 8
#define CHW 6300
#define TT 500
#define OUT 128
#define NO 1024
#define NK32 200          // total k32 steps (padded: 6300 -> 6400)
#define KSPLIT 8
#define NKC (NK32/KSPLIT) // 25 k32 per block

typedef __attribute__((ext_vector_type(8))) _Float16 f16x8;
typedef __attribute__((ext_vector_type(4))) float f32x4;

// ---------------- Kernel 1: pack W into MFMA A-fragment order ----------------
// Wp[hl][k32][osub][lane][8]; o=osub*16+(lane&15), c=k32*32+(lane>>4)*8+i
// hl=0: f16(W); hl=1: f16((W - f16(W)) * 2048). Zero-padded for c>=CHW.
__global__ __launch_bounds__(512) void packW(const float* __restrict__ W,
                                             _Float16* __restrict__ Wp) {
    const int tid = threadIdx.x;
    const int osub = tid >> 6;
    const int lane = tid & 63;
    const int k32 = blockIdx.x;
    const int hl = blockIdx.y;
    const int o = osub * 16 + (lane & 15);
    const int cb = k32 * 32 + (lane >> 4) * 8;

    union { _Float16 h[8]; uint4 u; } tmp;
#pragma unroll
    for (int i = 0; i < 8; i++) {
        int c = cb + i;
        float w = (c < CHW) ? W[(size_t)o * CHW + c] : 0.f;
        _Float16 hi = (_Float16)w;
        tmp.h[i] = (hl == 0) ? hi : (_Float16)((w - (float)hi) * 2048.f);
    }
    size_t lr = (((size_t)hl * NK32 + k32) * 8 + osub) * 64 + lane;
    *(uint4*)(Wp + lr * 8) = tmp.u;
}

// ---------------- Kernel 2: fused transpose+convert+MFMA GEMM ----------------
// v[t][n][o] = sum_c W[o][c] * x[n][c][t].  A = W (from Wp, L2-resident),
// B = x read DIRECTLY from [n][c][t] fp32 layout, cvt f16 in-reg, 8KB dbuf LDS.
// Block: 4 waves; tile 64t x 128o; KSPLIT=8. 3 blocks/CU for latency hiding.
__global__ __launch_bounds__(256, 3) void gemm(const float* __restrict__ x,
                                               const _Float16* __restrict__ Wp,
                                               float* __restrict__ vp) {
    const int L = blockIdx.x;                 // 0..511
    const int logical = (L & 7) * 64 + (L >> 3);
    const int tb = logical & 7;               // t-block (64 t)
    const int n  = (logical >> 3) & 7;        // batch
    const int ks = logical >> 6;              // k-split 0..7

    const int tid = threadIdx.x;
    const int wave = tid >> 6;
    const int lane = tid & 63;
    const int l15 = lane & 15;
    const int lg  = lane >> 4;                // 0..3
    const int k32_0 = ks * NKC;

    __shared__ _Float16 Bs[2][4][512];        // [buf][tfrag][lane*8] = 8KB

    const int t_st = tb * 64 + wave * 16 + l15;
    const bool t_ok = (t_st < TT);
    const float* xrow = x + (size_t)n * CHW * TT + t_st;   // + c*TT per element

    f32x4 acc[2][4][2] = {};                  // [ofrag][tfrag][hl]
    f16x8 Ar0[2][2], Ar1[2][2];               // A dbuf [ofrag][hl]
    float xvA[8], xvB[8];                     // x prefetch dbuf (static idx)

#define XLOAD(xv, it)                                                              \
    {                                                                              \
        const int cb_ = (k32_0 + (it)) * 32 + lg * 8;                              \
        if (((k32_0 + (it) + 1) * 32 <= CHW) && t_ok) {                            \
            _Pragma("unroll") for (int i = 0; i < 8; i++)                          \
                xv[i] = xrow[(size_t)(cb_ + i) * TT];                              \
        } else {                                                                   \
            _Pragma("unroll") for (int i = 0; i < 8; i++)                          \
                xv[i] = (t_ok && (cb_ + i) < CHW) ? xrow[(size_t)(cb_ + i) * TT]   \
                                                  : 0.f;                           \
        }                                                                          \
    }

#define XWRITE(xv, buf)                                                            \
    {                                                                              \
        union { _Float16 h[8]; uint4 u; } tw_;                                     \
        _Pragma("unroll") for (int i = 0; i < 8; i++) tw_.h[i] = (_Float16)xv[i];  \
        *(uint4*)&Bs[buf][wave][lane * 8] = tw_.u;                                 \
    }

#define ALOAD(Ar, it)                                                              \
    _Pragma("unroll") for (int of = 0; of < 2; of++)                               \
        _Pragma("unroll") for (int hl = 0; hl < 2; hl++)                           \
            Ar[of][hl] = *(const f16x8*)(Wp +                                      \
                ((((size_t)hl * NK32 + k32_0 + (it)) * 8 + wave * 2 + of) * 64 +   \
                 lane) * 8);

#define COMPUTE(buf, Ar)                                                           \
    {                                                                              \
        f16x8 bfr[4];                                                              \
        _Pragma("unroll") for (int tf = 0; tf < 4; tf++)                           \
            bfr[tf] = *(const f16x8*)&Bs[buf][tf][lane * 8];                       \
        _Pragma("unroll") for (int of = 0; of < 2; of++)                           \
            _Pragma("unroll") for (int tf = 0; tf < 4; tf++)                       \
                _Pragma("unroll") for (int hl = 0; hl < 2; hl++)                   \
                    acc[of][tf][hl] = __builtin_amdgcn_mfma_f32_16x16x32_f16(      \
                        Ar[of][hl], bfr[tf], acc[of][tf][hl], 0, 0, 0);            \
    }

    // prologue: it0 and it1 in flight
    XLOAD(xvA, 0)
    XLOAD(xvB, 1)
    ALOAD(Ar0, 0)
    XWRITE(xvA, 0)
    ALOAD(Ar1, 1)
    __syncthreads();

    for (int p = 0; p < 12; ++p) {
        const int it = 2 * p;
        XLOAD(xvA, it + 2)
        COMPUTE(0, Ar0)
        XWRITE(xvB, 1)
        ALOAD(Ar0, it + 2)
        __syncthreads();
        if (p < 11) { XLOAD(xvB, it + 3) }
        COMPUTE(1, Ar1)
        XWRITE(xvA, 0)
        if (p < 11) { ALOAD(Ar1, it + 3) }
        __syncthreads();
    }
    COMPUTE(0, Ar0)

    // epilogue: D layout col(l&15)=t, row=(l>>4)*4+r = o-within-frag
    const float inv = 1.f / 2048.f;
#pragma unroll
    for (int of = 0; of < 2; of++) {
        const int o0 = (wave * 2 + of) * 16 + lg * 4;
#pragma unroll
        for (int tf = 0; tf < 4; tf++) {
            const int t = tb * 64 + tf * 16 + l15;
            if (t < TT) {
                f32x4 vo;
#pragma unroll
                for (int r = 0; r < 4; r++)
                    vo[r] = acc[of][tf][0][r] + acc[of][tf][1][r] * inv;
                *(f32x4*)(vp + (((size_t)ks * TT + t) * NB + n) * OUT + o0) = vo;
            }
        }
    }
#undef XLOAD
#undef XWRITE
#undef ALOAD
#undef COMPUTE
}

// ---------------- Kernel 3: full-grid K-partial reduction ----------------
// vred[t][chain] = sum_{k=0..7} vp[k][t][chain]  (fixed order, deterministic)
__global__ __launch_bounds__(256) void reduceK(const float* __restrict__ vp,
                                               float* __restrict__ vred) {
    int i = blockIdx.x * 256 + threadIdx.x;      // float4 index, 128000 total
    const float4* p = (const float4*)vp;
    float4 a = p[i];
#pragma unroll
    for (int k = 1; k < KSPLIT; k++) {
        float4 b = p[(size_t)k * (TT * NO / 4) + i];
        a.x += b.x; a.y += b.y; a.z += b.z; a.w += b.w;
    }
    ((float4*)vred)[i] = a;
}

// ---------------- Kernel 4: wave-specialized alpha+spike scan ----------------
// 16 blocks x 512 thr. Wave 0: batched-register serial recursion (short critical
// path via G/H reformulation); waves 1-7 stage vred slabs into vbuf[t][chain].
#define SCN_RA 0.9048374180359595f       // exp(-0.1)
#define SCN_RACA 0.24596031111569496f    // RA*CA = 0.1*e^0.9
#define SCN_RS 0.36787944117144233f      // exp(-1)
#define SCN_RSCS -20.0f                  // RS*CS (CS = -20e)
#define SCN_RSCS2 -40.0f                 // 2*RS*CS
#define SCN_RSRSCS -7.3575888234288467f  // RS*RS*CS
#define SCN_TH 10.0f

#define CHAIN_STEP(i)                                                   \
    {                                                                   \
        float ua = Aa;                                                  \
        float w = fmaf(SCN_RS, G, ua);                                  \
        float u = sp ? (w + SCN_RSCS) : w;                              \
        bool sn = (u >= SCN_TH);                                        \
        sbuf[i][lane] = sn ? 1.f : 0.f;                                 \
        float Gb = fmaf(SCN_RS, G, H);                                  \
        G = sp ? (Gb + SCN_RSCS2) : Gb;                                 \
        float Hb = SCN_RS * H;                                          \
        H = sp ? (Hb + SCN_RSRSCS) : Hb;                                \
        sp = sn;                                                        \
        Ba = fmaf(SCN_RA, Ba, SCN_RACA * vv[i]);                        \
        Aa = fmaf(SCN_RA, Aa, Ba);                                      \
    }

__global__ __launch_bounds__(512) void scanspike(const float* __restrict__ vred,
                                                 float* __restrict__ out) {
    const int tid = threadIdx.x;
    const int wave = tid >> 6;
    const int lane = tid & 63;
    const int g0 = blockIdx.x * 64;

    __shared__ float vbuf[2][64][64];   // [buf][tloc][chain]
    __shared__ float sbuf[64][65];      // [tloc][chain+pad]

    for (int r = wave; r < 64; r += 8)
        vbuf[0][r][lane] = vred[(size_t)r * NO + g0 + lane];
    __syncthreads();

    float Aa = 0.f, Ba = 0.f, G = 0.f, H = 0.f;
    bool sp = false;

    for (int tb = 0; tb < 8; ++tb) {
        const int cur = tb & 1;
        const int t0 = tb * 64;
        const int cnt = (tb == 7) ? 52 : 64;

        if (wave == 0) {
            if (cnt == 64) {
                float vv[64];
#pragma unroll
                for (int i = 0; i < 64; ++i) vv[i] = vbuf[cur][i][lane];
#pragma unroll
                for (int i = 0; i < 64; ++i) CHAIN_STEP(i)
            } else {
                float vv[52];
#pragma unroll
                for (int i = 0; i < 52; ++i) vv[i] = vbuf[cur][i][lane];
#pragma unroll
                for (int i = 0; i < 52; ++i) CHAIN_STEP(i)
            }
        } else if (tb < 7) {
            const int nt0 = t0 + 64;
            const int ncnt = (tb == 6) ? 52 : 64;
            for (int r = wave - 1; r < ncnt; r += 7)
                vbuf[cur ^ 1][r][lane] = vred[(size_t)(nt0 + r) * NO + g0 + lane];
        }
        __syncthreads();

#pragma unroll
        for (int j = 0; j < 8; ++j) {
            int r = wave * 8 + j;
            int gr = g0 + r;
            int nn = gr >> 7;
            int oo = gr & 127;
            if (lane < cnt)
                out[((size_t)nn * OUT + oo) * TT + t0 + lane] = sbuf[lane][r];
        }
        __syncthreads();
    }
}

extern "C" void kernel_launch(void* const* d_in, const int* in_sizes, int n_in,
                              void* d_out, int out_size, void* d_ws, size_t ws_size,
                              hipStream_t stream) {
    const float* x = (const float*)d_in[0];   // [8,2,50,63,500] fp32
    const float* W = (const float*)d_in[1];   // [128,6300] fp32
    float* out = (float*)d_out;               // [8,128,1,1,500] fp32

    _Float16* Wp   = (_Float16*)d_ws;                        //  3,276,800 B
    float*    vp   = (float*)((char*)d_ws + 3276800);        // 16,384,000 B
    float*    vred = (float*)((char*)d_ws + 3276800 + 16384000);  // 2,048,000 B

    packW<<<dim3(NK32, 2), 512, 0, stream>>>(W, Wp);
    gemm<<<512, 256, 0, stream>>>(x, Wp, vp);
    reduceK<<<TT * NO / 4 / 256, 256, 0, stream>>>(vp, vred);
    scanspike<<<16, 512, 0, stream>>>(vred, out);
}

// Round 8
// 58.576 us; speedup vs baseline: 4.4637x; 1.0345x over previous
//
#include <hip/hip_runtime.h>

#define NB 8
#define CHW 6300
#define TT 500
#define OUT 128
#define NO 1024
#define NK32 200          // total k32 steps (padded: 6300 -> 6400)
#define KSPLIT 8
#define NKC (NK32/KSPLIT) // 25 k32 per block

typedef __attribute__((ext_vector_type(8))) _Float16 f16x8;
typedef __attribute__((ext_vector_type(4))) float f32x4;

// ---------------- Kernel 1: pack W into MFMA A-fragment order ----------------
// Wp[hl][k32][osub][lane][8]; o=osub*16+(lane&15), c=k32*32+(lane>>4)*8+i
// hl=0: f16(W); hl=1: f16((W - f16(W)) * 2048). Zero-padded for c>=CHW.
__global__ __launch_bounds__(512) void packW(const float* __restrict__ W,
                                             _Float16* __restrict__ Wp) {
    const int tid = threadIdx.x;
    const int osub = tid >> 6;
    const int lane = tid & 63;
    const int k32 = blockIdx.x;
    const int hl = blockIdx.y;
    const int o = osub * 16 + (lane & 15);
    const int cb = k32 * 32 + (lane >> 4) * 8;

    union { _Float16 h[8]; uint4 u; } tmp;
#pragma unroll
    for (int i = 0; i < 8; i++) {
        int c = cb + i;
        float w = (c < CHW) ? W[(size_t)o * CHW + c] : 0.f;
        _Float16 hi = (_Float16)w;
        tmp.h[i] = (hl == 0) ? hi : (_Float16)((w - (float)hi) * 2048.f);
    }
    size_t lr = (((size_t)hl * NK32 + k32) * 8 + osub) * 64 + lane;
    *(uint4*)(Wp + lr * 8) = tmp.u;
}

// ---------------- Kernel 2: fused transpose+convert+MFMA GEMM ----------------
// v[t][n][o] = sum_c W[o][c] * x[n][c][t].  A = W (from Wp, L2-resident),
// B = x read DIRECTLY from [n][c][t] fp32, cvt f16 in-reg, 8KB dbuf LDS.
// Depth-3 register prefetch (xvA/B/C, all static indices): step it issues
// loads for it+3 (~900cy ahead) so HBM latency is covered (Little's law).
__global__ __launch_bounds__(256, 2) void gemm(const float* __restrict__ x,
                                               const _Float16* __restrict__ Wp,
                                               float* __restrict__ vp) {
    const int L = blockIdx.x;                 // 0..511
    const int logical = (L & 7) * 64 + (L >> 3);
    const int tb = logical & 7;               // t-block (64 t)
    const int n  = (logical >> 3) & 7;        // batch
    const int ks = logical >> 6;              // k-split 0..7

    const int tid = threadIdx.x;
    const int wave = tid >> 6;
    const int lane = tid & 63;
    const int l15 = lane & 15;
    const int lg  = lane >> 4;                // 0..3
    const int k32_0 = ks * NKC;

    __shared__ _Float16 Bs[2][4][512];        // [buf][tfrag][lane*8] = 8KB

    const int t_st = tb * 64 + wave * 16 + l15;
    const bool t_ok = (t_st < TT);
    const float* xrow = x + (size_t)n * CHW * TT + t_st;   // + c*TT per element

    f32x4 acc[2][4][2] = {};                  // [ofrag][tfrag][hl]
    f16x8 Ar0[2][2], Ar1[2][2];               // A dbuf [ofrag][hl]
    float xvA[8], xvB[8], xvC[8];             // x prefetch, depth 3 (static idx)

#define XLOAD(xv, it)                                                              \
    {                                                                              \
        const int cb_ = (k32_0 + (it)) * 32 + lg * 8;                              \
        if (((k32_0 + (it) + 1) * 32 <= CHW) && t_ok) {                            \
            _Pragma("unroll") for (int i = 0; i < 8; i++)                          \
                xv[i] = xrow[(size_t)(cb_ + i) * TT];                              \
        } else {                                                                   \
            _Pragma("unroll") for (int i = 0; i < 8; i++)                          \
                xv[i] = (t_ok && (cb_ + i) < CHW) ? xrow[(size_t)(cb_ + i) * TT]   \
                                                  : 0.f;                           \
        }                                                                          \
    }

#define XWRITE(xv, buf)                                                            \
    {                                                                              \
        union { _Float16 h[8]; uint4 u; } tw_;                                     \
        _Pragma("unroll") for (int i = 0; i < 8; i++) tw_.h[i] = (_Float16)xv[i];  \
        *(uint4*)&Bs[buf][wave][lane * 8] = tw_.u;                                 \
    }

#define ALOAD(Ar, it)                                                              \
    _Pragma("unroll") for (int of = 0; of < 2; of++)                               \
        _Pragma("unroll") for (int hl = 0; hl < 2; hl++)                           \
            Ar[of][hl] = *(const f16x8*)(Wp +                                      \
                ((((size_t)hl * NK32 + k32_0 + (it)) * 8 + wave * 2 + of) * 64 +   \
                 lane) * 8);

#define COMPUTE(buf, Ar)                                                           \
    {                                                                              \
        f16x8 bfr[4];                                                              \
        _Pragma("unroll") for (int tf = 0; tf < 4; tf++)                           \
            bfr[tf] = *(const f16x8*)&Bs[buf][tf][lane * 8];                       \
        _Pragma("unroll") for (int of = 0; of < 2; of++)                           \
            _Pragma("unroll") for (int tf = 0; tf < 4; tf++)                       \
                _Pragma("unroll") for (int hl = 0; hl < 2; hl++)                   \
                    acc[of][tf][hl] = __builtin_amdgcn_mfma_f32_16x16x32_f16(      \
                        Ar[of][hl], bfr[tf], acc[of][tf][hl], 0, 0, 0);            \
    }

    // prologue: 3 x-phases in flight; step 0 staged to LDS[0]
    XLOAD(xvA, 0)
    XLOAD(xvB, 1)
    XLOAD(xvC, 2)
    ALOAD(Ar0, 0)
    XWRITE(xvA, 0)
    __syncthreads();

    // 4 iterations x 6 steps = steps 0..23 (parities exact: 6q = 0 mod 2,3)
    for (int q = 0; q < 4; ++q) {
        const int it0 = 6 * q;
        // s=0 (it=it0): compute LDS[0]/Ar0, write it+1->LDS[1], load it+3->xvA
        if (it0 + 3 <= 24) { XLOAD(xvA, it0 + 3) }
        COMPUTE(0, Ar0)
        XWRITE(xvB, 1)
        ALOAD(Ar1, it0 + 1)
        __syncthreads();
        // s=1
        if (it0 + 4 <= 24) { XLOAD(xvB, it0 + 4) }
        COMPUTE(1, Ar1)
        XWRITE(xvC, 0)
        ALOAD(Ar0, it0 + 2)
        __syncthreads();
        // s=2
        if (it0 + 5 <= 24) { XLOAD(xvC, it0 + 5) }
        COMPUTE(0, Ar0)
        XWRITE(xvA, 1)
        ALOAD(Ar1, it0 + 3)
        __syncthreads();
        // s=3
        if (it0 + 6 <= 24) { XLOAD(xvA, it0 + 6) }
        COMPUTE(1, Ar1)
        XWRITE(xvB, 0)
        ALOAD(Ar0, it0 + 4)
        __syncthreads();
        // s=4
        if (it0 + 7 <= 24) { XLOAD(xvB, it0 + 7) }
        COMPUTE(0, Ar0)
        XWRITE(xvC, 1)
        ALOAD(Ar1, it0 + 5)
        __syncthreads();
        // s=5
        if (it0 + 8 <= 24) { XLOAD(xvC, it0 + 8) }
        COMPUTE(1, Ar1)
        XWRITE(xvA, 0)
        ALOAD(Ar0, it0 + 6)
        __syncthreads();
    }
    // tail: it = 24 (LDS[0], Ar0)
    COMPUTE(0, Ar0)

    // epilogue: D layout col(l&15)=t, row=(l>>4)*4+r = o-within-frag
    const float inv = 1.f / 2048.f;
#pragma unroll
    for (int of = 0; of < 2; of++) {
        const int o0 = (wave * 2 + of) * 16 + lg * 4;
#pragma unroll
        for (int tf = 0; tf < 4; tf++) {
            const int t = tb * 64 + tf * 16 + l15;
            if (t < TT) {
                f32x4 vo;
#pragma unroll
                for (int r = 0; r < 4; r++)
                    vo[r] = acc[of][tf][0][r] + acc[of][tf][1][r] * inv;
                *(f32x4*)(vp + (((size_t)ks * TT + t) * NB + n) * OUT + o0) = vo;
            }
        }
    }
#undef XLOAD
#undef XWRITE
#undef ALOAD
#undef COMPUTE
}

// ---------------- Kernel 3: full-grid K-partial reduction ----------------
// vred[t][chain] = sum_{k=0..7} vp[k][t][chain]  (fixed order, deterministic)
__global__ __launch_bounds__(256) void reduceK(const float* __restrict__ vp,
                                               float* __restrict__ vred) {
    int i = blockIdx.x * 256 + threadIdx.x;      // float4 index, 128000 total
    const float4* p = (const float4*)vp;
    float4 a = p[i];
#pragma unroll
    for (int k = 1; k < KSPLIT; k++) {
        float4 b = p[(size_t)k * (TT * NO / 4) + i];
        a.x += b.x; a.y += b.y; a.z += b.z; a.w += b.w;
    }
    ((float4*)vred)[i] = a;
}

// ---------------- Kernel 4: wave-specialized alpha+spike scan ----------------
// 16 blocks x 512 thr. Wave 0: batched-register serial recursion (short critical
// path via G/H reformulation); waves 1-7 stage vred slabs into vbuf[t][chain].
#define SCN_RA 0.9048374180359595f       // exp(-0.1)
#define SCN_RACA 0.24596031111569496f    // RA*CA = 0.1*e^0.9
#define SCN_RS 0.36787944117144233f      // exp(-1)
#define SCN_RSCS -20.0f                  // RS*CS (CS = -20e)
#define SCN_RSCS2 -40.0f                 // 2*RS*CS
#define SCN_RSRSCS -7.3575888234288467f  // RS*RS*CS
#define SCN_TH 10.0f

#define CHAIN_STEP(i)                                                   \
    {                                                                   \
        float ua = Aa;                                                  \
        float w = fmaf(SCN_RS, G, ua);                                  \
        float u = sp ? (w + SCN_RSCS) : w;                              \
        bool sn = (u >= SCN_TH);                                        \
        sbuf[i][lane] = sn ? 1.f : 0.f;                                 \
        float Gb = fmaf(SCN_RS, G, H);                                  \
        G = sp ? (Gb + SCN_RSCS2) : Gb;                                 \
        float Hb = SCN_RS * H;                                          \
        H = sp ? (Hb + SCN_RSRSCS) : Hb;                                \
        sp = sn;                                                        \
        Ba = fmaf(SCN_RA, Ba, SCN_RACA * vv[i]);                        \
        Aa = fmaf(SCN_RA, Aa, Ba);                                      \
    }

__global__ __launch_bounds__(512) void scanspike(const float* __restrict__ vred,
                                                 float* __restrict__ out) {
    const int tid = threadIdx.x;
    const int wave = tid >> 6;
    const int lane = tid & 63;
    const int g0 = blockIdx.x * 64;

    __shared__ float vbuf[2][64][64];   // [buf][tloc][chain]
    __shared__ float sbuf[64][65];      // [tloc][chain+pad]

    for (int r = wave; r < 64; r += 8)
        vbuf[0][r][lane] = vred[(size_t)r * NO + g0 + lane];
    __syncthreads();

    float Aa = 0.f, Ba = 0.f, G = 0.f, H = 0.f;
    bool sp = false;

    for (int tb = 0; tb < 8; ++tb) {
        const int cur = tb & 1;
        const int t0 = tb * 64;
        const int cnt = (tb == 7) ? 52 : 64;

        if (wave == 0) {
            if (cnt == 64) {
                float vv[64];
#pragma unroll
                for (int i = 0; i < 64; ++i) vv[i] = vbuf[cur][i][lane];
#pragma unroll
                for (int i = 0; i < 64; ++i) CHAIN_STEP(i)
            } else {
                float vv[52];
#pragma unroll
                for (int i = 0; i < 52; ++i) vv[i] = vbuf[cur][i][lane];
#pragma unroll
                for (int i = 0; i < 52; ++i) CHAIN_STEP(i)
            }
        } else if (tb < 7) {
            const int nt0 = t0 + 64;
            const int ncnt = (tb == 6) ? 52 : 64;
            for (int r = wave - 1; r < ncnt; r += 7)
                vbuf[cur ^ 1][r][lane] = vred[(size_t)(nt0 + r) * NO + g0 + lane];
        }
        __syncthreads();

#pragma unroll
        for (int j = 0; j < 8; ++j) {
            int r = wave * 8 + j;
            int gr = g0 + r;
            int nn = gr >> 7;
            int oo = gr & 127;
            if (lane < cnt)
                out[((size_t)nn * OUT + oo) * TT + t0 + lane] = sbuf[lane][r];
        }
        __syncthreads();
    }
}

extern "C" void kernel_launch(void* const* d_in, const int* in_sizes, int n_in,
                              void* d_out, int out_size, void* d_ws, size_t ws_size,
                              hipStream_t stream) {
    const float* x = (const float*)d_in[0];   // [8,2,50,63,500] fp32
    const float* W = (const float*)d_in[1];   // [128,6300] fp32
    float* out = (float*)d_out;               // [8,128,1,1,500] fp32

    _Float16* Wp   = (_Float16*)d_ws;                        //  3,276,800 B
    float*    vp   = (float*)((char*)d_ws + 3276800);        // 16,384,000 B
    float*    vred = (float*)((char*)d_ws + 3276800 + 16384000);  // 2,048,000 B

    packW<<<dim3(NK32, 2), 512, 0, stream>>>(W, Wp);
    gemm<<<512, 256, 0, stream>>>(x, Wp, vp);
    reduceK<<<TT * NO / 4 / 256, 256, 0, stream>>>(vp, vred);
    scanspike<<<16, 512, 0, stream>>>(vred, out);
}

// Round 9
// 58.368 us; speedup vs baseline: 4.4796x; 1.0036x over previous
//
#include <hip/hip_runtime.h>

#define NB 8
#define CHW 6300
#define TT 500
#define OUT 128
#define NO 1024
#define NK32 200          // total k32 steps (padded: 6300 -> 6400)
#define KSPLIT 8
#define NKC (NK32/KSPLIT) // 25 k32 per block

typedef __attribute__((ext_vector_type(8))) _Float16 f16x8;
typedef __attribute__((ext_vector_type(4))) float f32x4;

// ---------------- Kernel 1: pack W into MFMA A-fragment order ----------------
// Wp[hl][k32][osub][lane][8]; o=osub*16+(lane&15), c=k32*32+(lane>>4)*8+i
// hl=0: f16(W); hl=1: f16((W - f16(W)) * 2048). Zero-padded for c>=CHW.
__global__ __launch_bounds__(512) void packW(const float* __restrict__ W,
                                             _Float16* __restrict__ Wp) {
    const int tid = threadIdx.x;
    const int osub = tid >> 6;
    const int lane = tid & 63;
    const int k32 = blockIdx.x;
    const int hl = blockIdx.y;
    const int o = osub * 16 + (lane & 15);
    const int cb = k32 * 32 + (lane >> 4) * 8;

    union { _Float16 h[8]; uint4 u; } tmp;
#pragma unroll
    for (int i = 0; i < 8; i++) {
        int c = cb + i;
        float w = (c < CHW) ? W[(size_t)o * CHW + c] : 0.f;
        _Float16 hi = (_Float16)w;
        tmp.h[i] = (hl == 0) ? hi : (_Float16)((w - (float)hi) * 2048.f);
    }
    size_t lr = (((size_t)hl * NK32 + k32) * 8 + osub) * 64 + lane;
    *(uint4*)(Wp + lr * 8) = tmp.u;
}

// ---------------- Kernel 2: fused transpose+convert+MFMA GEMM ----------------
// v[t][n][o] = sum_c W[o][c] * x[n][c][t].  A = W (from Wp, L2-resident).
// x path: coalesced dwordx4 rows -> Ls[32][65] fp32 (65-pad: all ds ops 2-way,
// free) -> TRANS reads per-lane frag pattern, cvt f16 -> Bs (identical layout
// and values as before -> bitwise-same output). 4-deep pipeline:
// XG(it+4) / DSW(it+2) / TRANS(it+1) / COMPUTE(it), one barrier per step.
// ALOAD issued BEFORE XG each step so Ar-waits don't drain x loads (FIFO).
__global__ __launch_bounds__(256, 2) void gemm(const float* __restrict__ x,
                                               const _Float16* __restrict__ Wp,
                                               float* __restrict__ vp) {
    const int L = blockIdx.x;                 // 0..511
    const int logical = (L & 7) * 64 + (L >> 3);
    const int tb = logical & 7;               // t-block (64 t)
    const int n  = (logical >> 3) & 7;        // batch
    const int ks = logical >> 6;              // k-split 0..7

    const int tid = threadIdx.x;
    const int wave = tid >> 6;
    const int lane = tid & 63;
    const int l15 = lane & 15;
    const int lg  = lane >> 4;                // 0..3
    const int rr  = lg;                       // staging row-within-4
    const int ch  = l15;                      // staging t-chunk (4 floats)
    const int k32_0 = ks * NKC;

    __shared__ float    Ls[2][32][65];        // raw fp32 tiles (16.6KB)
    __shared__ _Float16 Bs[2][4][512];        // f16 B-fragments (8KB)

    const float* xn = x + (size_t)n * CHW * TT;
    const int toff = tb * 64 + ch * 4;        // t byte-chunk base (float idx)
    const bool tbok = (tb < 7);               // tb==7: only ch<13 valid (t<500)

    f32x4 acc[2][4][2] = {};                  // [ofrag][tfrag][hl]
    f16x8 Ar0[2][2], Ar1[2][2];               // A dbuf [ofrag][hl]
    float4 sA[2], sB[2];                      // staging reg sets (XG parity)
    const float4 f4z = make_float4(0.f, 0.f, 0.f, 0.f);

#define XG(set, it)                                                                \
    {                                                                              \
        _Pragma("unroll") for (int p = 0; p < 2; p++) {                            \
            const int r_ = wave * 8 + p * 4 + rr;                                  \
            const int c_ = (k32_0 + (it)) * 32 + r_;                               \
            const bool v_ = (c_ < CHW) && (tbok || ch < 13);                       \
            set[p] = v_ ? *(const float4*)(xn + (size_t)c_ * TT + toff) : f4z;     \
        }                                                                          \
    }

#define DSW(set, bufL)                                                             \
    {                                                                              \
        _Pragma("unroll") for (int p = 0; p < 2; p++) {                            \
            const int r_ = wave * 8 + p * 4 + rr;                                  \
            Ls[bufL][r_][ch * 4 + 0] = set[p].x;                                   \
            Ls[bufL][r_][ch * 4 + 1] = set[p].y;                                   \
            Ls[bufL][r_][ch * 4 + 2] = set[p].z;                                   \
            Ls[bufL][r_][ch * 4 + 3] = set[p].w;                                   \
        }                                                                          \
    }

#define TRANS(bufL, bufB)                                                          \
    {                                                                              \
        float tv_[8];                                                              \
        _Pragma("unroll") for (int i = 0; i < 8; i++)                              \
            tv_[i] = Ls[bufL][lg * 8 + i][wave * 16 + l15];                        \
        union { _Float16 h[8]; uint4 u; } tc_;                                     \
        _Pragma("unroll") for (int i = 0; i < 8; i++)                              \
            tc_.h[i] = (_Float16)tv_[i];                                           \
        *(uint4*)&Bs[bufB][wave][lane * 8] = tc_.u;                                \
    }

#define ALOAD(Ar, it)                                                              \
    _Pragma("unroll") for (int of = 0; of < 2; of++)                               \
        _Pragma("unroll") for (int hl = 0; hl < 2; hl++)                           \
            Ar[of][hl] = *(const f16x8*)(Wp +                                      \
                ((((size_t)hl * NK32 + k32_0 + (it)) * 8 + wave * 2 + of) * 64 +   \
                 lane) * 8);

#define COMPUTE(buf, Ar)                                                           \
    {                                                                              \
        f16x8 bfr[4];                                                              \
        _Pragma("unroll") for (int tf = 0; tf < 4; tf++)                           \
            bfr[tf] = *(const f16x8*)&Bs[buf][tf][lane * 8];                       \
        _Pragma("unroll") for (int of = 0; of < 2; of++)                           \
            _Pragma("unroll") for (int tf = 0; tf < 4; tf++)                       \
                _Pragma("unroll") for (int hl = 0; hl < 2; hl++)                   \
                    acc[of][tf][hl] = __builtin_amdgcn_mfma_f32_16x16x32_f16(      \
                        Ar[of][hl], bfr[tf], acc[of][tf][hl], 0, 0, 0);            \
    }

    // prologue: tiles 0..3 in flight; Bs[0]=tile0, Ls[1]=tile1 ready after
    XG(sA, 0)
    XG(sB, 1)
    DSW(sA, 0)            // waits sA (one-time stall)
    XG(sA, 2)
    __syncthreads();      // Ls[0] (tile 0) visible
    TRANS(0, 0)           // Bs[0] = tile 0
    DSW(sB, 1)            // Ls[1] = tile 1
    XG(sB, 3)
    ALOAD(Ar0, 0)
    __syncthreads();      // Bs[0], Ls[1] visible

    for (int p = 0; p < 12; ++p) {
        const int it = 2 * p;
        // even step (cur=0): sA carries tile it+2 -> Ls[0]; XG(it+4)->sA
        ALOAD(Ar1, it + 1)
        DSW(sA, 0)                       // tile it+2 (always valid: it<=22)
        if (p <= 10) { XG(sA, it + 4) }
        TRANS(1, 1)                      // Bs[1] = tile it+1
        COMPUTE(0, Ar0)
        __syncthreads();
        // odd step (cur=1)
        ALOAD(Ar0, it + 2)
        if (p <= 10) { DSW(sB, 1) }      // tile it+3
        if (p <= 9)  { XG(sB, it + 5) }
        TRANS(0, 0)                      // Bs[0] = tile it+2
        COMPUTE(1, Ar1)
        __syncthreads();
    }
    // tail: it = 24
    COMPUTE(0, Ar0)

    // epilogue: D layout col(l&15)=t, row=(l>>4)*4+r = o-within-frag
    const float inv = 1.f / 2048.f;
#pragma unroll
    for (int of = 0; of < 2; of++) {
        const int o0 = (wave * 2 + of) * 16 + lg * 4;
#pragma unroll
        for (int tf = 0; tf < 4; tf++) {
            const int t = tb * 64 + tf * 16 + l15;
            if (t < TT) {
                f32x4 vo;
#pragma unroll
                for (int r = 0; r < 4; r++)
                    vo[r] = acc[of][tf][0][r] + acc[of][tf][1][r] * inv;
                *(f32x4*)(vp + (((size_t)ks * TT + t) * NB + n) * OUT + o0) = vo;
            }
        }
    }
#undef XG
#undef DSW
#undef TRANS
#undef ALOAD
#undef COMPUTE
}

// ---------------- Kernel 3: full-grid K-partial reduction ----------------
// vred[t][chain] = sum_{k=0..7} vp[k][t][chain]  (fixed order, deterministic)
__global__ __launch_bounds__(256) void reduceK(const float* __restrict__ vp,
                                               float* __restrict__ vred) {
    int i = blockIdx.x * 256 + threadIdx.x;      // float4 index, 128000 total
    const float4* p = (const float4*)vp;
    float4 a = p[i];
#pragma unroll
    for (int k = 1; k < KSPLIT; k++) {
        float4 b = p[(size_t)k * (TT * NO / 4) + i];
        a.x += b.x; a.y += b.y; a.z += b.z; a.w += b.w;
    }
    ((float4*)vred)[i] = a;
}

// ---------------- Kernel 4: wave-specialized alpha+spike scan ----------------
// 16 blocks x 512 thr. Wave 0: batched-register serial recursion (short critical
// path via G/H reformulation); waves 1-7 stage vred slabs into vbuf[t][chain].
#define SCN_RA 0.9048374180359595f       // exp(-0.1)
#define SCN_RACA 0.24596031111569496f    // RA*CA = 0.1*e^0.9
#define SCN_RS 0.36787944117144233f      // exp(-1)
#define SCN_RSCS -20.0f                  // RS*CS (CS = -20e)
#define SCN_RSCS2 -40.0f                 // 2*RS*CS
#define SCN_RSRSCS -7.3575888234288467f  // RS*RS*CS
#define SCN_TH 10.0f

#define CHAIN_STEP(i)                                                   \
    {                                                                   \
        float ua = Aa;                                                  \
        float w = fmaf(SCN_RS, G, ua);                                  \
        float u = sp ? (w + SCN_RSCS) : w;                              \
        bool sn = (u >= SCN_TH);                                        \
        sbuf[i][lane] = sn ? 1.f : 0.f;                                 \
        float Gb = fmaf(SCN_RS, G, H);                                  \
        G = sp ? (Gb + SCN_RSCS2) : Gb;                                 \
        float Hb = SCN_RS * H;                                          \
        H = sp ? (Hb + SCN_RSRSCS) : Hb;                                \
        sp = sn;                                                        \
        Ba = fmaf(SCN_RA, Ba, SCN_RACA * vv[i]);                        \
        Aa = fmaf(SCN_RA, Aa, Ba);                                      \
    }

__global__ __launch_bounds__(512) void scanspike(const float* __restrict__ vred,
                                                 float* __restrict__ out) {
    const int tid = threadIdx.x;
    const int wave = tid >> 6;
    const int lane = tid & 63;
    const int g0 = blockIdx.x * 64;

    __shared__ float vbuf[2][64][64];   // [buf][tloc][chain]
    __shared__ float sbuf[64][65];      // [tloc][chain+pad]

    for (int r = wave; r < 64; r += 8)
        vbuf[0][r][lane] = vred[(size_t)r * NO + g0 + lane];
    __syncthreads();

    float Aa = 0.f, Ba = 0.f, G = 0.f, H = 0.f;
    bool sp = false;

    for (int tb = 0; tb < 8; ++tb) {
        const int cur = tb & 1;
        const int t0 = tb * 64;
        const int cnt = (tb == 7) ? 52 : 64;

        if (wave == 0) {
            if (cnt == 64) {
                float vv[64];
#pragma unroll
                for (int i = 0; i < 64; ++i) vv[i] = vbuf[cur][i][lane];
#pragma unroll
                for (int i = 0; i < 64; ++i) CHAIN_STEP(i)
            } else {
                float vv[52];
#pragma unroll
                for (int i = 0; i < 52; ++i) vv[i] = vbuf[cur][i][lane];
#pragma unroll
                for (int i = 0; i < 52; ++i) CHAIN_STEP(i)
            }
        } else if (tb < 7) {
            const int nt0 = t0 + 64;
            const int ncnt = (tb == 6) ? 52 : 64;
            for (int r = wave - 1; r < ncnt; r += 7)
                vbuf[cur ^ 1][r][lane] = vred[(size_t)(nt0 + r) * NO + g0 + lane];
        }
        __syncthreads();

#pragma unroll
        for (int j = 0; j < 8; ++j) {
            int r = wave * 8 + j;
            int gr = g0 + r;
            int nn = gr >> 7;
            int oo = gr & 127;
            if (lane < cnt)
                out[((size_t)nn * OUT + oo) * TT + t0 + lane] = sbuf[lane][r];
        }
        __syncthreads();
    }
}

extern "C" void kernel_launch(void* const* d_in, const int* in_sizes, int n_in,
                              void* d_out, int out_size, void* d_ws, size_t ws_size,
                              hipStream_t stream) {
    const float* x = (const float*)d_in[0];   // [8,2,50,63,500] fp32
    const float* W = (const float*)d_in[1];   // [128,6300] fp32
    float* out = (float*)d_out;               // [8,128,1,1,500] fp32

    _Float16* Wp   = (_Float16*)d_ws;                        //  3,276,800 B
    float*    vp   = (float*)((char*)d_ws + 3276800);        // 16,384,000 B
    float*    vred = (float*)((char*)d_ws + 3276800 + 16384000);  // 2,048,000 B

    packW<<<dim3(NK32, 2), 512, 0, stream>>>(W, Wp);
    gemm<<<512, 256, 0, stream>>>(x, Wp, vp);
    reduceK<<<TT * NO / 4 / 256, 256, 0, stream>>>(vp, vred);
    scanspike<<<16, 512, 0, stream>>>(vred, out);
}

// Round 10
// 58.326 us; speedup vs baseline: 4.4828x; 1.0007x over previous
//
#include <hip/hip_runtime.h>

#define NB 8
#define CHW 6300
#define TT 500
#define OUT 128
#define NO 1024
#define NK32 200          // total k32 steps (padded: 6300 -> 6400)
#define KSPLIT 8
#define NKC (NK32/KSPLIT) // 25 k32 per block

typedef __attribute__((ext_vector_type(8))) _Float16 f16x8;
typedef __attribute__((ext_vector_type(4))) float f32x4;

// Raw workgroup barrier draining ONLY lgkmcnt (LDS writes), not vmcnt:
// keeps global-load prefetches in flight across the barrier. All VMEM results
// land in registers whose uses get compiler-inserted COUNTED vmcnt waits.
__device__ __forceinline__ void wg_barrier_lgkm() {
    asm volatile("s_waitcnt lgkmcnt(0)" ::: "memory");
    __builtin_amdgcn_s_barrier();
}

// ---------------- Kernel 1: pack W into MFMA A-fragment order ----------------
// Wp[hl][k32][osub][lane][8]; o=osub*16+(lane&15), c=k32*32+(lane>>4)*8+i
// hl=0: f16(W); hl=1: f16((W - f16(W)) * 2048). Zero-padded for c>=CHW.
__global__ __launch_bounds__(512) void packW(const float* __restrict__ W,
                                             _Float16* __restrict__ Wp) {
    const int tid = threadIdx.x;
    const int osub = tid >> 6;
    const int lane = tid & 63;
    const int k32 = blockIdx.x;
    const int hl = blockIdx.y;
    const int o = osub * 16 + (lane & 15);
    const int cb = k32 * 32 + (lane >> 4) * 8;

    union { _Float16 h[8]; uint4 u; } tmp;
#pragma unroll
    for (int i = 0; i < 8; i++) {
        int c = cb + i;
        float w = (c < CHW) ? W[(size_t)o * CHW + c] : 0.f;
        _Float16 hi = (_Float16)w;
        tmp.h[i] = (hl == 0) ? hi : (_Float16)((w - (float)hi) * 2048.f);
    }
    size_t lr = (((size_t)hl * NK32 + k32) * 8 + osub) * 64 + lane;
    *(uint4*)(Wp + lr * 8) = tmp.u;
}

// ---------------- Kernel 2: fused transpose+convert+MFMA GEMM ----------------
// Identical dataflow to round 9 (coalesced dwordx4 -> Ls -> TRANS -> Bs ->
// MFMA, 4-deep), but ALL main-loop barriers are lgkm-only raw barriers so the
// XG prefetches actually stay outstanding across steps (counted vmcnt on use).
__global__ __launch_bounds__(256, 2) void gemm(const float* __restrict__ x,
                                               const _Float16* __restrict__ Wp,
                                               float* __restrict__ vp) {
    const int L = blockIdx.x;                 // 0..511
    const int logical = (L & 7) * 64 + (L >> 3);
    const int tb = logical & 7;               // t-block (64 t)
    const int n  = (logical >> 3) & 7;        // batch
    const int ks = logical >> 6;              // k-split 0..7

    const int tid = threadIdx.x;
    const int wave = tid >> 6;
    const int lane = tid & 63;
    const int l15 = lane & 15;
    const int lg  = lane >> 4;                // 0..3
    const int rr  = lg;                       // staging row-within-4
    const int ch  = l15;                      // staging t-chunk (4 floats)
    const int k32_0 = ks * NKC;

    __shared__ float    Ls[2][32][65];        // raw fp32 tiles (16.6KB)
    __shared__ _Float16 Bs[2][4][512];        // f16 B-fragments (8KB)

    const float* xn = x + (size_t)n * CHW * TT;
    const int toff = tb * 64 + ch * 4;        // t chunk base (float idx)
    const bool tbok = (tb < 7);               // tb==7: only ch<13 valid (t<500)

    f32x4 acc[2][4][2] = {};                  // [ofrag][tfrag][hl]
    f16x8 Ar0[2][2], Ar1[2][2];               // A dbuf [ofrag][hl]
    float4 sA[2], sB[2];                      // staging reg sets (XG parity)
    const float4 f4z = make_float4(0.f, 0.f, 0.f, 0.f);

#define XG(set, it)                                                                \
    {                                                                              \
        _Pragma("unroll") for (int p = 0; p < 2; p++) {                            \
            const int r_ = wave * 8 + p * 4 + rr;                                  \
            const int c_ = (k32_0 + (it)) * 32 + r_;                               \
            const bool v_ = (c_ < CHW) && (tbok || ch < 13);                       \
            set[p] = v_ ? *(const float4*)(xn + (size_t)c_ * TT + toff) : f4z;     \
        }                                                                          \
    }

#define DSW(set, bufL)                                                             \
    {                                                                              \
        _Pragma("unroll") for (int p = 0; p < 2; p++) {                            \
            const int r_ = wave * 8 + p * 4 + rr;                                  \
            Ls[bufL][r_][ch * 4 + 0] = set[p].x;                                   \
            Ls[bufL][r_][ch * 4 + 1] = set[p].y;                                   \
            Ls[bufL][r_][ch * 4 + 2] = set[p].z;                                   \
            Ls[bufL][r_][ch * 4 + 3] = set[p].w;                                   \
        }                                                                          \
    }

#define TRANS(bufL, bufB)                                                          \
    {                                                                              \
        float tv_[8];                                                              \
        _Pragma("unroll") for (int i = 0; i < 8; i++)                              \
            tv_[i] = Ls[bufL][lg * 8 + i][wave * 16 + l15];                        \
        union { _Float16 h[8]; uint4 u; } tc_;                                     \
        _Pragma("unroll") for (int i = 0; i < 8; i++)                              \
            tc_.h[i] = (_Float16)tv_[i];                                           \
        *(uint4*)&Bs[bufB][wave][lane * 8] = tc_.u;                                \
    }

#define ALOAD(Ar, it)                                                              \
    _Pragma("unroll") for (int of = 0; of < 2; of++)                               \
        _Pragma("unroll") for (int hl = 0; hl < 2; hl++)                           \
            Ar[of][hl] = *(const f16x8*)(Wp +                                      \
                ((((size_t)hl * NK32 + k32_0 + (it)) * 8 + wave * 2 + of) * 64 +   \
                 lane) * 8);

#define COMPUTE(buf, Ar)                                                           \
    {                                                                              \
        f16x8 bfr[4];                                                              \
        _Pragma("unroll") for (int tf = 0; tf < 4; tf++)                           \
            bfr[tf] = *(const f16x8*)&Bs[buf][tf][lane * 8];                       \
        _Pragma("unroll") for (int of = 0; of < 2; of++)                           \
            _Pragma("unroll") for (int tf = 0; tf < 4; tf++)                       \
                _Pragma("unroll") for (int hl = 0; hl < 2; hl++)                   \
                    acc[of][tf][hl] = __builtin_amdgcn_mfma_f32_16x16x32_f16(      \
                        Ar[of][hl], bfr[tf], acc[of][tf][hl], 0, 0, 0);            \
    }

    // prologue: tiles 0..3 in flight; Bs[0]=tile0, Ls[1]=tile1 ready after
    XG(sA, 0)
    XG(sB, 1)
    DSW(sA, 0)            // waits sA (one-time stall, counted)
    XG(sA, 2)
    wg_barrier_lgkm();    // Ls[0] (tile 0) visible
    TRANS(0, 0)           // Bs[0] = tile 0
    DSW(sB, 1)            // Ls[1] = tile 1
    XG(sB, 3)
    ALOAD(Ar0, 0)
    wg_barrier_lgkm();    // Bs[0], Ls[1] visible

    for (int p = 0; p < 12; ++p) {
        const int it = 2 * p;
        // even step (cur=0): sA carries tile it+2 -> Ls[0]; XG(it+4)->sA
        ALOAD(Ar1, it + 1)
        DSW(sA, 0)                       // tile it+2 (always valid: it<=22)
        if (p <= 10) { XG(sA, it + 4) }
        TRANS(1, 1)                      // Bs[1] = tile it+1
        COMPUTE(0, Ar0)
        wg_barrier_lgkm();
        // odd step (cur=1)
        ALOAD(Ar0, it + 2)
        if (p <= 10) { DSW(sB, 1) }      // tile it+3
        if (p <= 9)  { XG(sB, it + 5) }
        TRANS(0, 0)                      // Bs[0] = tile it+2
        COMPUTE(1, Ar1)
        wg_barrier_lgkm();
    }
    // tail: it = 24
    COMPUTE(0, Ar0)

    // epilogue: D layout col(l&15)=t, row=(l>>4)*4+r = o-within-frag
    const float inv = 1.f / 2048.f;
#pragma unroll
    for (int of = 0; of < 2; of++) {
        const int o0 = (wave * 2 + of) * 16 + lg * 4;
#pragma unroll
        for (int tf = 0; tf < 4; tf++) {
            const int t = tb * 64 + tf * 16 + l15;
            if (t < TT) {
                f32x4 vo;
#pragma unroll
                for (int r = 0; r < 4; r++)
                    vo[r] = acc[of][tf][0][r] + acc[of][tf][1][r] * inv;
                *(f32x4*)(vp + (((size_t)ks * TT + t) * NB + n) * OUT + o0) = vo;
            }
        }
    }
#undef XG
#undef DSW
#undef TRANS
#undef ALOAD
#undef COMPUTE
}

// ---------------- Kernel 3: full-grid K-partial reduction ----------------
// vred[t][chain] = sum_{k=0..7} vp[k][t][chain]  (fixed order, deterministic)
__global__ __launch_bounds__(256) void reduceK(const float* __restrict__ vp,
                                               float* __restrict__ vred) {
    int i = blockIdx.x * 256 + threadIdx.x;      // float4 index, 128000 total
    const float4* p = (const float4*)vp;
    float4 a = p[i];
#pragma unroll
    for (int k = 1; k < KSPLIT; k++) {
        float4 b = p[(size_t)k * (TT * NO / 4) + i];
        a.x += b.x; a.y += b.y; a.z += b.z; a.w += b.w;
    }
    ((float4*)vred)[i] = a;
}

// ---------------- Kernel 4: wave-specialized alpha+spike scan ----------------
// 16 blocks x 512 thr. Wave 0: batched-register serial recursion (short critical
// path via G/H reformulation); waves 1-7 stage vred slabs into vbuf[t][chain].
#define SCN_RA 0.9048374180359595f       // exp(-0.1)
#define SCN_RACA 0.24596031111569496f    // RA*CA = 0.1*e^0.9
#define SCN_RS 0.36787944117144233f      // exp(-1)
#define SCN_RSCS -20.0f                  // RS*CS (CS = -20e)
#define SCN_RSCS2 -40.0f                 // 2*RS*CS
#define SCN_RSRSCS -7.3575888234288467f  // RS*RS*CS
#define SCN_TH 10.0f

#define CHAIN_STEP(i)                                                   \
    {                                                                   \
        float ua = Aa;                                                  \
        float w = fmaf(SCN_RS, G, ua);                                  \
        float u = sp ? (w + SCN_RSCS) : w;                              \
        bool sn = (u >= SCN_TH);                                        \
        sbuf[i][lane] = sn ? 1.f : 0.f;                                 \
        float Gb = fmaf(SCN_RS, G, H);                                  \
        G = sp ? (Gb + SCN_RSCS2) : Gb;                                 \
        float Hb = SCN_RS * H;                                          \
        H = sp ? (Hb + SCN_RSRSCS) : Hb;                                \
        sp = sn;                                                        \
        Ba = fmaf(SCN_RA, Ba, SCN_RACA * vv[i]);                        \
        Aa = fmaf(SCN_RA, Aa, Ba);                                      \
    }

__global__ __launch_bounds__(512) void scanspike(const float* __restrict__ vred,
                                                 float* __restrict__ out) {
    const int tid = threadIdx.x;
    const int wave = tid >> 6;
    const int lane = tid & 63;
    const int g0 = blockIdx.x * 64;

    __shared__ float vbuf[2][64][64];   // [buf][tloc][chain]
    __shared__ float sbuf[64][65];      // [tloc][chain+pad]

    for (int r = wave; r < 64; r += 8)
        vbuf[0][r][lane] = vred[(size_t)r * NO + g0 + lane];
    __syncthreads();

    float Aa = 0.f, Ba = 0.f, G = 0.f, H = 0.f;
    bool sp = false;

    for (int tb = 0; tb < 8; ++tb) {
        const int cur = tb & 1;
        const int t0 = tb * 64;
        const int cnt = (tb == 7) ? 52 : 64;

        if (wave == 0) {
            if (cnt == 64) {
                float vv[64];
#pragma unroll
                for (int i = 0; i < 64; ++i) vv[i] = vbuf[cur][i][lane];
#pragma unroll
                for (int i = 0; i < 64; ++i) CHAIN_STEP(i)
            } else {
                float vv[52];
#pragma unroll
                for (int i = 0; i < 52; ++i) vv[i] = vbuf[cur][i][lane];
#pragma unroll
                for (int i = 0; i < 52; ++i) CHAIN_STEP(i)
            }
        } else if (tb < 7) {
            const int nt0 = t0 + 64;
            const int ncnt = (tb == 6) ? 52 : 64;
            for (int r = wave - 1; r < ncnt; r += 7)
                vbuf[cur ^ 1][r][lane] = vred[(size_t)(nt0 + r) * NO + g0 + lane];
        }
        __syncthreads();

#pragma unroll
        for (int j = 0; j < 8; ++j) {
            int r = wave * 8 + j;
            int gr = g0 + r;
            int nn = gr >> 7;
            int oo = gr & 127;
            if (lane < cnt)
                out[((size_t)nn * OUT + oo) * TT + t0 + lane] = sbuf[lane][r];
        }
        __syncthreads();
    }
}

extern "C" void kernel_launch(void* const* d_in, const int* in_sizes, int n_in,
                              void* d_out, int out_size, void* d_ws, size_t ws_size,
                              hipStream_t stream) {
    const float* x = (const float*)d_in[0];   // [8,2,50,63,500] fp32
    const float* W = (const float*)d_in[1];   // [128,6300] fp32
    float* out = (float*)d_out;               // [8,128,1,1,500] fp32

    _Float16* Wp   = (_Float16*)d_ws;                        //  3,276,800 B
    float*    vp   = (float*)((char*)d_ws + 3276800);        // 16,384,000 B
    float*    vred = (float*)((char*)d_ws + 3276800 + 16384000);  // 2,048,000 B

    packW<<<dim3(NK32, 2), 512, 0, stream>>>(W, Wp);
    gemm<<<512, 256, 0, stream>>>(x, Wp, vp);
    reduceK<<<TT * NO / 4 / 256, 256, 0, stream>>>(vp, vred);
    scanspike<<<16, 512, 0, stream>>>(vred, out);
}